// Round 4
// baseline (592.273 us; speedup 1.0000x reference)
//
#include <hip/hip_runtime.h>
#include <hip/hip_bf16.h>

#define DEVFN __device__ __forceinline__

constexpr int NN = 50000;
constexpr int NE = 800000;
constexpr int NQ = 200000;
constexpr long MP = 50048;   // NN padded to multiple of 128

typedef __attribute__((ext_vector_type(8))) short bf16x8;
typedef __attribute__((ext_vector_type(4))) float f32x4;
typedef __attribute__((address_space(1))) const void gv_t;
typedef __attribute__((address_space(3))) void lv_t;

DEVFN float lrelu(float x) { return x > 0.f ? x : 0.01f * x; }
DEVFN float sigmoidf(float x) { return 1.f / (1.f + __expf(-x)); }

DEVFN short f2b(float v) {
    __hip_bfloat16 h = __float2bfloat16(v);
    return *reinterpret_cast<short*>(&h);
}
DEVFN float b2f(short s) {
    union { unsigned u; float f; } z;
    z.u = ((unsigned)(unsigned short)s) << 16;
    return z.f;
}
DEVFN void gld16(const void* g, void* l) {
    __builtin_amdgcn_global_load_lds((gv_t*)g, (lv_t*)l, 16, 0, 0);
}

// ---------------------------------------------------------------------------
// fp32 -> bf16 row copy with zero-filled padding rows
// ---------------------------------------------------------------------------
__global__ void f2b_rows(const float* __restrict__ in, short* __restrict__ out,
                         long n, long ntot) {
    long i = (long)blockIdx.x * 256 + threadIdx.x;
    if (i < n) out[i] = f2b(in[i]);
    else if (i < ntot) out[i] = 0;
}

// fp32 [NN][H] -> bf16 into right half of AP [MP][2H]: out[r*2H + H + c]
__global__ void f2b_strided(const float* __restrict__ in, short* __restrict__ out,
                            int H, long n) {
    long i = (long)blockIdx.x * 256 + threadIdx.x;
    if (i >= n) return;
    long r = i / H;
    int c = i % H;
    out[r * 2 * H + H + c] = f2b(in[i]);
}

// fp32 [K][N] -> bf16 [N][K] (transposed weights)
__global__ void wT_b(const float* __restrict__ W, short* __restrict__ Wt, int K, int N) {
    int i = blockIdx.x * 256 + threadIdx.x;
    if (i >= N * K) return;
    int n = i / K, k = i % K;
    Wt[i] = f2b(W[(long)k * N + n]);
}

// ---------------------------------------------------------------------------
// Build interleaved GRU weight matrix W1 [4H][2H] (bf16, row-major over K2=2H).
// Row n' = g16*64 + chunk*16 + cl; real col c = g16*16+cl; chunks: r,z,n,hn.
//   chunk0 (r):  k<H ? Wih[k][c]      : Whh[k-H][c]
//   chunk1 (z):  k<H ? Wih[k][H+c]    : Whh[k-H][H+c]
//   chunk2 (in): k<H ? Wih[k][2H+c]   : 0
//   chunk3 (hn): k<H ? 0              : Whh[k-H][2H+c]
// ---------------------------------------------------------------------------
template <int H>
__global__ void build_gruW(const float* __restrict__ Wih, const float* __restrict__ Whh,
                           short* __restrict__ W1) {
    constexpr int K2 = 2 * H, W3 = 3 * H;
    int i = blockIdx.x * 256 + threadIdx.x;
    if (i >= 4 * H * K2) return;
    int np = i / K2, k = i % K2;
    int g16 = np >> 6, chunk = (np >> 4) & 3, cl = np & 15;
    int c = g16 * 16 + cl;
    float v;
    if (chunk == 0)      v = (k < H) ? Wih[(long)k * W3 + c]         : Whh[(long)(k - H) * W3 + c];
    else if (chunk == 1) v = (k < H) ? Wih[(long)k * W3 + H + c]     : Whh[(long)(k - H) * W3 + H + c];
    else if (chunk == 2) v = (k < H) ? Wih[(long)k * W3 + 2 * H + c] : 0.f;
    else                 v = (k < H) ? 0.f                           : Whh[(long)(k - H) * W3 + 2 * H + c];
    W1[i] = f2b(v);
}

// ---------------------------------------------------------------------------
// bf16 MFMA GEMM, double-buffered 2-phase: C = epi(A[Mpad][K] @ Bt[Nt][K]^T + bias)
// BM=BN=128, BK=32, 4 waves (2x2), each wave 64x64 (4x4 16x16 frags).
// ---------------------------------------------------------------------------
template <int EPI, bool OUTF, bool OUTB>
__global__ __launch_bounds__(256)
void gemm_mfma(const short* __restrict__ A, const short* __restrict__ Bt,
               const float* __restrict__ bias, float* __restrict__ Cf,
               short* __restrict__ Cb, int M, int Nt, int K) {
    __shared__ alignas(16) short As[2][4096];
    __shared__ alignas(16) short Bs[2][4096];
    const int tid = threadIdx.x;
    const int lane = tid & 63, w = tid >> 6;
    const int wr = w >> 1, wc = w & 1;
    const long row0 = (long)blockIdx.x * 128;
    const long col0 = (long)blockIdx.y * 128;

    f32x4 acc[4][4] = {};

    const int ra = tid >> 2;            // 0..63
    const int kc = (tid & 3) * 8;       // element offset in K
    const short* gA = A + (row0 + ra) * (long)K + kc;
    const short* gB = Bt + (col0 + ra) * (long)K + kc;
    const long half = 64 * (long)K;

    auto stage = [&](int b, int k0) {
        gld16(gA + k0, &As[b][tid * 8]);
        gld16(gA + half + k0, &As[b][2048 + tid * 8]);
        gld16(gB + k0, &Bs[b][tid * 8]);
        gld16(gB + half + k0, &Bs[b][2048 + tid * 8]);
    };

    stage(0, 0);
    int cur = 0;
    const int l15 = lane & 15, kq = (lane >> 4) * 8;
    for (int k0 = 0; k0 < K; k0 += 32) {
        __syncthreads();                    // buf[cur] ready; buf[cur^1] free
        if (k0 + 32 < K) stage(cur ^ 1, k0 + 32);
        bf16x8 af[4], bfr[4];
#pragma unroll
        for (int i = 0; i < 4; ++i)
            af[i] = *(const bf16x8*)&As[cur][(wr * 64 + i * 16 + l15) * 32 + kq];
#pragma unroll
        for (int j = 0; j < 4; ++j)
            bfr[j] = *(const bf16x8*)&Bs[cur][(wc * 64 + j * 16 + l15) * 32 + kq];
#pragma unroll
        for (int i = 0; i < 4; ++i)
#pragma unroll
            for (int j = 0; j < 4; ++j)
                acc[i][j] = __builtin_amdgcn_mfma_f32_16x16x32_bf16(af[i], bfr[j], acc[i][j], 0, 0, 0);
        cur ^= 1;
    }

    const int cr = (lane >> 4) * 4, cc = lane & 15;
#pragma unroll
    for (int i = 0; i < 4; ++i) {
#pragma unroll
        for (int j = 0; j < 4; ++j) {
            const long col = col0 + wc * 64 + j * 16 + cc;
            float bv = (EPI == 1) ? bias[col] : 0.f;
#pragma unroll
            for (int r = 0; r < 4; ++r) {
                const long row = row0 + wr * 64 + i * 16 + cr + r;
                float v = acc[i][j][r];
                if (EPI == 1) v = lrelu(v + bv);
                if (OUTF && row < M) Cf[row * Nt + col] = v;
                if (OUTB) Cb[row * Nt + col] = f2b(v);
            }
        }
    }
}

// ---------------------------------------------------------------------------
// Wide fused GRU: G = AP[MP][2H] @ W1[4H][2H]^T with gating epilogue.
// Block: 128 rows x 128 n'-cols (= 32 real cols x 4 chunks).
// Wave quadrant: 64 rows x (16 real cols x 4 chunks); frag j == chunk j.
// out = (1-z)*n + z*prev  (prev read fp32)
// ---------------------------------------------------------------------------
template <int H, bool WRITEB>
__global__ __launch_bounds__(256)
void gru_wide(const short* __restrict__ AP, const short* __restrict__ W1,
              const float* __restrict__ prevf,
              const float* __restrict__ bih, const float* __restrict__ bhh,
              float* __restrict__ outF, short* __restrict__ outB, int M) {
    constexpr int K2 = 2 * H;
    __shared__ alignas(16) short As[2][4096];
    __shared__ alignas(16) short Bs[2][4096];
    const int tid = threadIdx.x;
    const int lane = tid & 63, w = tid >> 6;
    const int wr = w >> 1, wc = w & 1;
    const long row0 = (long)blockIdx.x * 128;
    const long col0 = (long)blockIdx.y * 128;   // in n' space

    f32x4 acc[4][4] = {};

    const int ra = tid >> 2;
    const int kc = (tid & 3) * 8;
    const short* gA = AP + (row0 + ra) * (long)K2 + kc;
    const short* gB = W1 + (col0 + ra) * (long)K2 + kc;
    const long half = 64 * (long)K2;

    auto stage = [&](int b, int k0) {
        gld16(gA + k0, &As[b][tid * 8]);
        gld16(gA + half + k0, &As[b][2048 + tid * 8]);
        gld16(gB + k0, &Bs[b][tid * 8]);
        gld16(gB + half + k0, &Bs[b][2048 + tid * 8]);
    };

    stage(0, 0);
    int cur = 0;
    const int l15 = lane & 15, kq = (lane >> 4) * 8;
    for (int k0 = 0; k0 < K2; k0 += 32) {
        __syncthreads();
        if (k0 + 32 < K2) stage(cur ^ 1, k0 + 32);
        bf16x8 af[4], bfr[4];
#pragma unroll
        for (int i = 0; i < 4; ++i)
            af[i] = *(const bf16x8*)&As[cur][(wr * 64 + i * 16 + l15) * 32 + kq];
#pragma unroll
        for (int j = 0; j < 4; ++j)
            bfr[j] = *(const bf16x8*)&Bs[cur][(wc * 64 + j * 16 + l15) * 32 + kq];
#pragma unroll
        for (int i = 0; i < 4; ++i)
#pragma unroll
            for (int j = 0; j < 4; ++j)
                acc[i][j] = __builtin_amdgcn_mfma_f32_16x16x32_bf16(af[i], bfr[j], acc[i][j], 0, 0, 0);
        cur ^= 1;
    }

    // gating epilogue: frag j = chunk j (0=r, 1=z, 2=inn, 3=hn)
    const int cr = (lane >> 4) * 4;
    const int c = (int)(blockIdx.y * 32) + wc * 16 + (lane & 15);  // real col
    const float bsr = bih[c] + bhh[c];
    const float bsz = bih[H + c] + bhh[H + c];
    const float bin = bih[2 * H + c];
    const float bhn = bhh[2 * H + c];
#pragma unroll
    for (int i = 0; i < 4; ++i) {
#pragma unroll
        for (int r = 0; r < 4; ++r) {
            const long row = row0 + wr * 64 + i * 16 + cr + r;
            if (row >= M) continue;
            float rg = sigmoidf(acc[i][0][r] + bsr);
            float zg = sigmoidf(acc[i][1][r] + bsz);
            float ng = tanhf(acc[i][2][r] + bin + rg * (acc[i][3][r] + bhn));
            float o = (1.f - zg) * ng + zg * prevf[row * (long)H + c];
            outF[row * (long)H + c] = o;
            if (WRITEB) outB[row * (long)H + c] = f2b(o);
        }
    }
}

// ---------------------------------------------------------------------------
// CSR build: count -> scan -> fill (edge list sorted by destination col)
// ---------------------------------------------------------------------------
__global__ void cnt_kernel(const int* __restrict__ cols, int* __restrict__ cnt, int E) {
    int e = blockIdx.x * 256 + threadIdx.x;
    if (e < E) atomicAdd(&cnt[cols[e]], 1);
}

__global__ void dinv_kernel(const int* __restrict__ cnt, float* __restrict__ dinv, int n) {
    int i = blockIdx.x * 256 + threadIdx.x;
    if (i < n) dinv[i] = rsqrtf((float)cnt[i] + 1.0f);   // +1 self-loop
}

__global__ void scan1(const int* __restrict__ cnt, int* __restrict__ off,
                      int* __restrict__ bsum, int n) {
    __shared__ int sm[256];
    int i = blockIdx.x * 256 + threadIdx.x;
    int v = (i < n) ? cnt[i] : 0;
    sm[threadIdx.x] = v;
    __syncthreads();
    for (int s = 1; s < 256; s <<= 1) {
        int t = (threadIdx.x >= s) ? sm[threadIdx.x - s] : 0;
        __syncthreads();
        sm[threadIdx.x] += t;
        __syncthreads();
    }
    if (i < n) off[i + 1] = sm[threadIdx.x];
    if (threadIdx.x == 255) bsum[blockIdx.x] = sm[255];
}

__global__ void scan2(int* __restrict__ bsum, int nb) {
    __shared__ int sm[256];
    int v = (threadIdx.x < nb) ? bsum[threadIdx.x] : 0;
    sm[threadIdx.x] = v;
    __syncthreads();
    for (int s = 1; s < 256; s <<= 1) {
        int t = (threadIdx.x >= s) ? sm[threadIdx.x - s] : 0;
        __syncthreads();
        sm[threadIdx.x] += t;
        __syncthreads();
    }
    if (threadIdx.x < nb) bsum[threadIdx.x] = sm[threadIdx.x] - v;  // exclusive
}

__global__ void scan3(int* __restrict__ off, const int* __restrict__ bsum, int n) {
    int i = blockIdx.x * 256 + threadIdx.x;
    if (i < n) off[i + 1] += bsum[blockIdx.x];
    if (i == 0) off[0] = 0;
}

__global__ void fill_csr(const int* __restrict__ rows, const int* __restrict__ cols,
                         const float* __restrict__ dinv, const int* __restrict__ off,
                         int* __restrict__ cursor, int* __restrict__ srow,
                         float* __restrict__ snorm, int E) {
    int e = blockIdx.x * 256 + threadIdx.x;
    if (e >= E) return;
    int r = rows[e], c = cols[e];
    int p = off[c] + atomicAdd(&cursor[c], 1);
    srow[p] = r;
    snorm[p] = dinv[r] * dinv[c];
}

// ---------------------------------------------------------------------------
// Gather-aggregate, fused epilogue, strided output (into AP left half):
// out[c*OS + f] = bf16(lrelu(sum_e hw[srow[e]]*snorm[e] + hw[c]*dinv[c]^2 + bias))
// ---------------------------------------------------------------------------
template <int H, int OS>
__global__ __launch_bounds__(256)
void gather_agg(const short* __restrict__ hwb, const int* __restrict__ off,
                const int* __restrict__ srow, const float* __restrict__ snorm,
                const float* __restrict__ dinv, const float* __restrict__ bias,
                short* __restrict__ aggb, int n) {
    constexpr int V = H / 64;           // feats per lane (4 or 2)
    typedef __attribute__((ext_vector_type(V))) short svt;
    int t = blockIdx.x * 256 + threadIdx.x;
    int c = t >> 6, l = t & 63;
    if (c >= n) return;
    const int fo = l * V;
    float acc[V];
    {
        float dd = dinv[c] * dinv[c];
        svt v = *(const svt*)&hwb[(long)c * H + fo];
#pragma unroll
        for (int i = 0; i < V; ++i) acc[i] = b2f(v[i]) * dd;
    }
    int e = off[c];
    const int e1 = off[c + 1];
    for (; e + 1 < e1; e += 2) {
        int r0 = srow[e], r1 = srow[e + 1];
        float n0 = snorm[e], n1 = snorm[e + 1];
        svt v0 = *(const svt*)&hwb[(long)r0 * H + fo];
        svt v1 = *(const svt*)&hwb[(long)r1 * H + fo];
#pragma unroll
        for (int i = 0; i < V; ++i)
            acc[i] += b2f(v0[i]) * n0 + b2f(v1[i]) * n1;
    }
    if (e < e1) {
        int r0 = srow[e];
        float n0 = snorm[e];
        svt v0 = *(const svt*)&hwb[(long)r0 * H + fo];
#pragma unroll
        for (int i = 0; i < V; ++i) acc[i] += b2f(v0[i]) * n0;
    }
    svt o;
#pragma unroll
    for (int i = 0; i < V; ++i) o[i] = f2b(lrelu(acc[i] + bias[fo + i]));
    *(svt*)&aggb[(long)c * OS + fo] = o;
}

// ---------------------------------------------------------------------------
// Edge scores: one 64-lane wave per query edge
// ---------------------------------------------------------------------------
__global__ void edge_score(const float* __restrict__ emb2, const int* __restrict__ eli,
                           const float* __restrict__ ea, const float* __restrict__ pw,
                           const float* __restrict__ pb, float* __restrict__ scores, int Q) {
    int t = blockIdx.x * 256 + threadIdx.x;
    int e = t >> 6, l = t & 63;
    if (e >= Q) return;
    int s = eli[e], d = eli[Q + e];
    float acc = 0.f;
#pragma unroll
    for (int i = 0; i < 2; ++i) {
        int f = l + 64 * i;
        acc += emb2[(long)s * 128 + f] * pw[f] + emb2[(long)d * 128 + f] * pw[128 + f];
    }
    if (l < 16) acc += ea[(long)e * 16 + l] * pw[256 + l];
#pragma unroll
    for (int off = 32; off > 0; off >>= 1) acc += __shfl_down(acc, off);
    if (l == 0) scores[e] = acc + pb[0];
}

// ---------------------------------------------------------------------------

extern "C" void kernel_launch(void* const* d_in, const int* in_sizes, int n_in,
                              void* d_out, int out_size, void* d_ws, size_t ws_size,
                              hipStream_t stream) {
    const float* x       = (const float*)d_in[0];
    const int*   ei      = (const int*)d_in[1];
    const int*   eli     = (const int*)d_in[2];
    const float* eattr   = (const float*)d_in[3];
    const float* prev1   = (const float*)d_in[4];
    const float* prev2   = (const float*)d_in[5];
    const float* pre1_W  = (const float*)d_in[6];
    const float* pre1_b  = (const float*)d_in[7];
    const float* pre2_W  = (const float*)d_in[8];
    const float* pre2_b  = (const float*)d_in[9];
    const float* conv1_W = (const float*)d_in[10];
    const float* conv1_b = (const float*)d_in[11];
    const float* conv2_W = (const float*)d_in[12];
    const float* conv2_b = (const float*)d_in[13];
    const float* g1_Wih  = (const float*)d_in[14];
    const float* g1_Whh  = (const float*)d_in[15];
    const float* g1_bih  = (const float*)d_in[16];
    const float* g1_bhh  = (const float*)d_in[17];
    const float* g2_Wih  = (const float*)d_in[18];
    const float* g2_Whh  = (const float*)d_in[19];
    const float* g2_bih  = (const float*)d_in[20];
    const float* g2_bhh  = (const float*)d_in[21];
    const float* post_W  = (const float*)d_in[22];
    const float* post_b  = (const float*)d_in[23];

    float* out    = (float*)d_out;
    float* scores = out;                      // [NQ]
    float* emb1   = out + NQ;                 // [N,256]
    float* emb2   = emb1 + (long)NN * 256;    // [N,128]

    // workspace layout (bytes)
    char* ws = (char*)d_ws;
    const long S256 = MP * 256 * 2;           // 25,624,576
    const long S128 = MP * 128 * 2;           // 12,812,288
    short* R2  = (short*)ws;                          // h1b -> emb1b
    short* R3  = (short*)(ws + S256);                 // h2b -> hw2b
    short* R1  = (short*)(ws + S256 + S128);          // xb -> hw1b -> AP2
    short* AP1 = (short*)(ws + 2 * S256 + S128);      // [MP][512]
    short* AP2 = R1;                                  // [MP][256], aliases R1
    char*  wts = ws + 4 * S256 + S128;
    short* pre1T  = (short*)wts;            // [256][256]
    short* pre2T  = pre1T + 256 * 256;      // [128][256]
    short* conv1T = pre2T + 128 * 256;      // [256][128]
    short* conv2T = conv1T + 256 * 128;     // [128][256]
    short* W1g1   = conv2T + 128 * 256;     // [1024][512]
    short* W1g2   = W1g1 + 1024 * 512;      // [512][256]
    float* dinv   = (float*)(W1g2 + 512 * 256);   // [NN]
    int*   cnt    = (int*)(dinv + NN);            // [NN]
    int*   off    = cnt + NN;                     // [NN+1]
    int*   cursor = off + NN + 1;                 // [NN]
    int*   bsum   = cursor + NN;                  // [256]
    int*   srow   = bsum + 256;                   // [NE]
    float* snorm  = (float*)(srow + NE);          // [NE]

    const int* rows = ei;
    const int* cols = ei + NE;

    dim3 blk(256);
    const int NB = (NN + 255) / 256;   // 196

    // --- conversions / weight builds ---
    f2b_rows<<<(MP * 256 + 255) / 256, blk, 0, stream>>>(x, R1, (long)NN * 256, MP * 256);
    wT_b<<<(256 * 256 + 255) / 256, blk, 0, stream>>>(pre1_W, pre1T, 256, 256);
    wT_b<<<(128 * 256 + 255) / 256, blk, 0, stream>>>(pre2_W, pre2T, 256, 128);
    wT_b<<<(256 * 128 + 255) / 256, blk, 0, stream>>>(conv1_W, conv1T, 128, 256);
    wT_b<<<(128 * 256 + 255) / 256, blk, 0, stream>>>(conv2_W, conv2T, 256, 128);
    build_gruW<256><<<(1024 * 512 + 255) / 256, blk, 0, stream>>>(g1_Wih, g1_Whh, W1g1);
    build_gruW<128><<<(512 * 256 + 255) / 256, blk, 0, stream>>>(g2_Wih, g2_Whh, W1g2);

    // --- CSR build (once, reused by both layers) ---
    hipMemsetAsync(cnt, 0, NN * sizeof(int), stream);
    cnt_kernel<<<(NE + 255) / 256, blk, 0, stream>>>(cols, cnt, NE);
    dinv_kernel<<<NB, blk, 0, stream>>>(cnt, dinv, NN);
    scan1<<<NB, blk, 0, stream>>>(cnt, off, bsum, NN);
    scan2<<<1, blk, 0, stream>>>(bsum, NB);
    scan3<<<NB, blk, 0, stream>>>(off, bsum, NN);
    hipMemsetAsync(cursor, 0, NN * sizeof(int), stream);
    fill_csr<<<(NE + 255) / 256, blk, 0, stream>>>(rows, cols, dinv, off, cursor, srow, snorm, NE);

    // --- dense pre-layers ---
    gemm_mfma<1, false, true><<<dim3(391, 2), blk, 0, stream>>>(R1, pre1T, pre1_b, nullptr, R2, NN, 256, 256);
    gemm_mfma<1, false, true><<<dim3(391, 1), blk, 0, stream>>>(R2, pre2T, pre2_b, nullptr, R3, NN, 128, 256);
    gemm_mfma<0, false, true><<<dim3(391, 2), blk, 0, stream>>>(R3, conv1T, nullptr, nullptr, R1, NN, 256, 128);

    // --- GCN1 aggregate -> AP1 left half; prev1 -> AP1 right half ---
    gather_agg<256, 512><<<(NN + 3) / 4, blk, 0, stream>>>(R1, off, srow, snorm, dinv, conv1_b, AP1, NN);
    f2b_strided<<<((long)NN * 256 + 255) / 256, blk, 0, stream>>>(prev1, AP1, 256, (long)NN * 256);

    // --- GRU1 (wide fused) -> emb1 fp32 + emb1b bf16 (R2) ---
    gru_wide<256, true><<<dim3(391, 8), blk, 0, stream>>>(AP1, W1g1, prev1, g1_bih, g1_bhh,
                                                          emb1, R2, NN);

    // --- conv2 ---
    gemm_mfma<0, false, true><<<dim3(391, 1), blk, 0, stream>>>(R2, conv2T, nullptr, nullptr, R3, NN, 128, 256);

    // --- GCN2 aggregate -> AP2 left half; prev2 -> AP2 right half ---
    gather_agg<128, 256><<<(NN + 3) / 4, blk, 0, stream>>>(R3, off, srow, snorm, dinv, conv2_b, AP2, NN);
    f2b_strided<<<((long)NN * 128 + 255) / 256, blk, 0, stream>>>(prev2, AP2, 128, (long)NN * 128);

    // --- GRU2 (wide fused) -> emb2 fp32 ---
    gru_wide<128, false><<<dim3(391, 4), blk, 0, stream>>>(AP2, W1g2, prev2, g2_bih, g2_bhh,
                                                           emb2, nullptr, NN);

    // --- edge scores ---
    edge_score<<<NQ / 4, blk, 0, stream>>>(emb2, eli, eattr, post_W, post_b, scores, NQ);
}

// Round 5
// 584.674 us; speedup vs baseline: 1.0130x; 1.0130x over previous
//
#include <hip/hip_runtime.h>
#include <hip/hip_bf16.h>

#define DEVFN __device__ __forceinline__

constexpr int NN = 50000;
constexpr int NE = 800000;
constexpr int NQ = 200000;
constexpr long MP = 50048;   // NN padded to multiple of 128

typedef __attribute__((ext_vector_type(8))) short bf16x8;
typedef __attribute__((ext_vector_type(2))) short s16x2;
typedef __attribute__((ext_vector_type(4))) float f32x4;
typedef __attribute__((address_space(1))) const void gv_t;
typedef __attribute__((address_space(3))) void lv_t;

DEVFN float lrelu(float x) { return x > 0.f ? x : 0.01f * x; }
DEVFN float sigmoidf(float x) { return 1.f / (1.f + __expf(-x)); }

DEVFN short f2b(float v) {
    __hip_bfloat16 h = __float2bfloat16(v);
    return *reinterpret_cast<short*>(&h);
}
DEVFN float b2f(short s) {
    union { unsigned u; float f; } z;
    z.u = ((unsigned)(unsigned short)s) << 16;
    return z.f;
}
DEVFN void gld16(const void* g, void* l) {
    __builtin_amdgcn_global_load_lds((gv_t*)g, (lv_t*)l, 16, 0, 0);
}

// ---------------------------------------------------------------------------
// fp32 -> bf16 row copy with zero-filled padding rows
// ---------------------------------------------------------------------------
__global__ void f2b_rows(const float* __restrict__ in, short* __restrict__ out,
                         long n, long ntot) {
    long i = (long)blockIdx.x * 256 + threadIdx.x;
    if (i < n) out[i] = f2b(in[i]);
    else if (i < ntot) out[i] = 0;
}

// fp32 [NN][H] -> bf16 into right half of AP [MP][2H]: out[r*2H + H + c]
__global__ void f2b_strided(const float* __restrict__ in, short* __restrict__ out,
                            int H, long n) {
    long i = (long)blockIdx.x * 256 + threadIdx.x;
    if (i >= n) return;
    long r = i / H;
    int c = i % H;
    out[r * 2 * H + H + c] = f2b(in[i]);
}

// fp32 [K][N] -> bf16 [N][K] (transposed weights)
__global__ void wT_b(const float* __restrict__ W, short* __restrict__ Wt, int K, int N) {
    int i = blockIdx.x * 256 + threadIdx.x;
    if (i >= N * K) return;
    int n = i / K, k = i % K;
    Wt[i] = f2b(W[(long)k * N + n]);
}

// ---------------------------------------------------------------------------
// Build interleaved GRU weight matrix W1 [4H][2H] (bf16, row-major over K2=2H).
// Row n' = g16*64 + chunk*16 + cl; real col c = g16*16+cl; chunks: r,z,n,hn.
// ---------------------------------------------------------------------------
template <int H>
__global__ void build_gruW(const float* __restrict__ Wih, const float* __restrict__ Whh,
                           short* __restrict__ W1) {
    constexpr int K2 = 2 * H, W3 = 3 * H;
    int i = blockIdx.x * 256 + threadIdx.x;
    if (i >= 4 * H * K2) return;
    int np = i / K2, k = i % K2;
    int g16 = np >> 6, chunk = (np >> 4) & 3, cl = np & 15;
    int c = g16 * 16 + cl;
    float v;
    if (chunk == 0)      v = (k < H) ? Wih[(long)k * W3 + c]         : Whh[(long)(k - H) * W3 + c];
    else if (chunk == 1) v = (k < H) ? Wih[(long)k * W3 + H + c]     : Whh[(long)(k - H) * W3 + H + c];
    else if (chunk == 2) v = (k < H) ? Wih[(long)k * W3 + 2 * H + c] : 0.f;
    else                 v = (k < H) ? 0.f                           : Whh[(long)(k - H) * W3 + 2 * H + c];
    W1[i] = f2b(v);
}

// ---------------------------------------------------------------------------
// bf16 MFMA GEMM, 2-phase dbuf + XOR slot swizzle:
// C = epi(A[Mpad][K] @ Bt[Nt][K]^T + bias); BM=BN=128, BK=32, 4 waves.
// bf16 C-output written with row stride obS.
// ---------------------------------------------------------------------------
template <int EPI, bool OUTB>
__global__ __launch_bounds__(256)
void gemm_mfma(const short* __restrict__ A, const short* __restrict__ Bt,
               const float* __restrict__ bias,
               short* __restrict__ Cb, int M, int Nt, int K, int obS) {
    __shared__ alignas(16) short As[2][4096];
    __shared__ alignas(16) short Bs[2][4096];
    const int tid = threadIdx.x;
    const int lane = tid & 63, w = tid >> 6;
    const int wr = w >> 1, wc = w & 1;
    const long row0 = (long)blockIdx.x * 128;
    const long col0 = (long)blockIdx.y * 128;

    f32x4 acc[4][4] = {};

    // staging: thread -> (row = tid>>2, slot = tid&3); pre-swizzled global slot
    const int kcs = ((tid & 3) ^ ((tid >> 3) & 3)) * 8;
    const short* gA = A + (row0 + (tid >> 2)) * (long)K + kcs;
    const short* gB = Bt + (col0 + (tid >> 2)) * (long)K + kcs;
    const long half = 64 * (long)K;

    auto stage = [&](int b, int k0) {
        gld16(gA + k0, &As[b][tid * 8]);
        gld16(gA + half + k0, &As[b][2048 + tid * 8]);
        gld16(gB + k0, &Bs[b][tid * 8]);
        gld16(gB + half + k0, &Bs[b][2048 + tid * 8]);
    };

    stage(0, 0);
    int cur = 0;
    const int l15 = lane & 15;
    const int kq = (((lane >> 4) ^ ((l15 >> 1) & 3)) * 8);   // swizzled slot on read
    for (int k0 = 0; k0 < K; k0 += 32) {
        __syncthreads();
        if (k0 + 32 < K) stage(cur ^ 1, k0 + 32);
        bf16x8 af[4], bfr[4];
#pragma unroll
        for (int i = 0; i < 4; ++i)
            af[i] = *(const bf16x8*)&As[cur][(wr * 64 + i * 16 + l15) * 32 + kq];
#pragma unroll
        for (int j = 0; j < 4; ++j)
            bfr[j] = *(const bf16x8*)&Bs[cur][(wc * 64 + j * 16 + l15) * 32 + kq];
#pragma unroll
        for (int i = 0; i < 4; ++i)
#pragma unroll
            for (int j = 0; j < 4; ++j)
                acc[i][j] = __builtin_amdgcn_mfma_f32_16x16x32_bf16(af[i], bfr[j], acc[i][j], 0, 0, 0);
        cur ^= 1;
    }

    const int cr = (lane >> 4) * 4, cc = lane & 15;
#pragma unroll
    for (int i = 0; i < 4; ++i) {
#pragma unroll
        for (int j = 0; j < 4; ++j) {
            const long col = col0 + wc * 64 + j * 16 + cc;
            float bv = (EPI == 1) ? bias[col] : 0.f;
#pragma unroll
            for (int r = 0; r < 4; ++r) {
                const long row = row0 + wr * 64 + i * 16 + cr + r;
                float v = acc[i][j][r];
                if (EPI == 1) v = lrelu(v + bv);
                if (OUTB) Cb[row * obS + col] = f2b(v);
            }
        }
    }
}

// ---------------------------------------------------------------------------
// Wide fused GRU, 512 threads, tile 128 rows x 256 n'-cols, 8 waves (2x4).
// G = AP[MP][2H] @ W1[4H][2H]^T; frag j == gate chunk j (r,z,inn,hn).
// ---------------------------------------------------------------------------
template <int H, bool WRITEB>
__global__ __launch_bounds__(512)
void gru_wide(const short* __restrict__ AP, const short* __restrict__ W1,
              const float* __restrict__ prevf,
              const float* __restrict__ bih, const float* __restrict__ bhh,
              float* __restrict__ outF, short* __restrict__ outB, int M) {
    constexpr int K2 = 2 * H;
    __shared__ alignas(16) short As[2][4096];   // 128 x 32
    __shared__ alignas(16) short Bs[2][8192];   // 256 x 32
    const int tid = threadIdx.x;
    const int lane = tid & 63, w = tid >> 6;
    const int wr = w >> 2, wc = w & 3;
    const long row0 = (long)blockIdx.x * 128;
    const long col0 = (long)blockIdx.y * 256;   // n' space

    f32x4 acc[4][4] = {};

    const int kcs = ((tid & 3) ^ ((tid >> 3) & 3)) * 8;
    const short* gA  = AP + (row0 + (tid >> 2)) * (long)K2 + kcs;
    const short* gB0 = W1 + (col0 + (tid >> 2)) * (long)K2 + kcs;
    const short* gB1 = W1 + (col0 + 128 + (tid >> 2)) * (long)K2 + kcs;

    auto stage = [&](int b, int k0) {
        gld16(gA + k0, &As[b][tid * 8]);
        gld16(gB0 + k0, &Bs[b][tid * 8]);
        gld16(gB1 + k0, &Bs[b][4096 + tid * 8]);
    };

    stage(0, 0);
    int cur = 0;
    const int l15 = lane & 15;
    const int kq = (((lane >> 4) ^ ((l15 >> 1) & 3)) * 8);
    for (int k0 = 0; k0 < K2; k0 += 32) {
        __syncthreads();
        if (k0 + 32 < K2) stage(cur ^ 1, k0 + 32);
        bf16x8 af[4], bfr[4];
#pragma unroll
        for (int i = 0; i < 4; ++i)
            af[i] = *(const bf16x8*)&As[cur][(wr * 64 + i * 16 + l15) * 32 + kq];
#pragma unroll
        for (int j = 0; j < 4; ++j)
            bfr[j] = *(const bf16x8*)&Bs[cur][(wc * 64 + j * 16 + l15) * 32 + kq];
#pragma unroll
        for (int i = 0; i < 4; ++i)
#pragma unroll
            for (int j = 0; j < 4; ++j)
                acc[i][j] = __builtin_amdgcn_mfma_f32_16x16x32_bf16(af[i], bfr[j], acc[i][j], 0, 0, 0);
        cur ^= 1;
    }

    // gating epilogue: frag j = chunk j (0=r, 1=z, 2=inn, 3=hn)
    const int cr = (lane >> 4) * 4;
    const int c = (int)blockIdx.y * 64 + wc * 16 + (lane & 15);  // real col
    const float bsr = bih[c] + bhh[c];
    const float bsz = bih[H + c] + bhh[H + c];
    const float bin = bih[2 * H + c];
    const float bhn = bhh[2 * H + c];
#pragma unroll
    for (int i = 0; i < 4; ++i) {
#pragma unroll
        for (int r = 0; r < 4; ++r) {
            const long row = row0 + wr * 64 + i * 16 + cr + r;
            if (row >= M) continue;
            float rg = sigmoidf(acc[i][0][r] + bsr);
            float zg = sigmoidf(acc[i][1][r] + bsz);
            float ng = tanhf(acc[i][2][r] + bin + rg * (acc[i][3][r] + bhn));
            float o = (1.f - zg) * ng + zg * prevf[row * (long)H + c];
            outF[row * (long)H + c] = o;
            if (WRITEB) outB[row * (long)H + c] = f2b(o);
        }
    }
}

// ---------------------------------------------------------------------------
// CSR build: count -> scan -> fill (edge list sorted by destination col)
// ---------------------------------------------------------------------------
__global__ void cnt_kernel(const int* __restrict__ cols, int* __restrict__ cnt, int E) {
    int e = blockIdx.x * 256 + threadIdx.x;
    if (e < E) atomicAdd(&cnt[cols[e]], 1);
}

__global__ void dinv_kernel(const int* __restrict__ cnt, float* __restrict__ dinv, int n) {
    int i = blockIdx.x * 256 + threadIdx.x;
    if (i < n) dinv[i] = rsqrtf((float)cnt[i] + 1.0f);   // +1 self-loop
}

__global__ void scan1(const int* __restrict__ cnt, int* __restrict__ off,
                      int* __restrict__ bsum, int n) {
    __shared__ int sm[256];
    int i = blockIdx.x * 256 + threadIdx.x;
    int v = (i < n) ? cnt[i] : 0;
    sm[threadIdx.x] = v;
    __syncthreads();
    for (int s = 1; s < 256; s <<= 1) {
        int t = (threadIdx.x >= s) ? sm[threadIdx.x - s] : 0;
        __syncthreads();
        sm[threadIdx.x] += t;
        __syncthreads();
    }
    if (i < n) off[i + 1] = sm[threadIdx.x];
    if (threadIdx.x == 255) bsum[blockIdx.x] = sm[255];
}

__global__ void scan2(int* __restrict__ bsum, int nb) {
    __shared__ int sm[256];
    int v = (threadIdx.x < nb) ? bsum[threadIdx.x] : 0;
    sm[threadIdx.x] = v;
    __syncthreads();
    for (int s = 1; s < 256; s <<= 1) {
        int t = (threadIdx.x >= s) ? sm[threadIdx.x - s] : 0;
        __syncthreads();
        sm[threadIdx.x] += t;
        __syncthreads();
    }
    if (threadIdx.x < nb) bsum[threadIdx.x] = sm[threadIdx.x] - v;  // exclusive
}

__global__ void scan3(int* __restrict__ off, const int* __restrict__ bsum, int n) {
    int i = blockIdx.x * 256 + threadIdx.x;
    if (i < n) off[i + 1] += bsum[blockIdx.x];
    if (i == 0) off[0] = 0;
}

__global__ void fill_csr(const int* __restrict__ rows, const int* __restrict__ cols,
                         const float* __restrict__ dinv, const int* __restrict__ off,
                         int* __restrict__ cursor, int* __restrict__ srow,
                         float* __restrict__ snorm, int E) {
    int e = blockIdx.x * 256 + threadIdx.x;
    if (e >= E) return;
    int r = rows[e], c = cols[e];
    int p = off[c] + atomicAdd(&cursor[c], 1);
    srow[p] = r;
    snorm[p] = dinv[r] * dinv[c];
}

// ---------------------------------------------------------------------------
// Gather-aggregate over H=128 feats, one wave per destination node.
// EPI=false: raw weighted sum (incl self-loop).  EPI=true: +bias, lrelu.
// Output row stride OS.
// ---------------------------------------------------------------------------
template <int OS, bool EPI>
__global__ __launch_bounds__(256)
void gather_agg(const short* __restrict__ hwb, const int* __restrict__ off,
                const int* __restrict__ srow, const float* __restrict__ snorm,
                const float* __restrict__ dinv, const float* __restrict__ bias,
                short* __restrict__ aggb, int n) {
    constexpr int H = 128, V = 2;
    int t = blockIdx.x * 256 + threadIdx.x;
    int c = t >> 6, l = t & 63;
    if (c >= n) return;
    const int fo = l * V;
    float acc0, acc1;
    {
        float dd = dinv[c] * dinv[c];
        s16x2 v = *(const s16x2*)&hwb[(long)c * H + fo];
        acc0 = b2f(v[0]) * dd;
        acc1 = b2f(v[1]) * dd;
    }
    int e = off[c];
    const int e1 = off[c + 1];
    for (; e + 1 < e1; e += 2) {
        int r0 = srow[e], r1 = srow[e + 1];
        float n0 = snorm[e], n1 = snorm[e + 1];
        s16x2 v0 = *(const s16x2*)&hwb[(long)r0 * H + fo];
        s16x2 v1 = *(const s16x2*)&hwb[(long)r1 * H + fo];
        acc0 += b2f(v0[0]) * n0 + b2f(v1[0]) * n1;
        acc1 += b2f(v0[1]) * n0 + b2f(v1[1]) * n1;
    }
    if (e < e1) {
        int r0 = srow[e];
        float n0 = snorm[e];
        s16x2 v0 = *(const s16x2*)&hwb[(long)r0 * H + fo];
        acc0 += b2f(v0[0]) * n0;
        acc1 += b2f(v0[1]) * n0;
    }
    s16x2 o;
    if (EPI) {
        o[0] = f2b(lrelu(acc0 + bias[fo]));
        o[1] = f2b(lrelu(acc1 + bias[fo + 1]));
    } else {
        o[0] = f2b(acc0);
        o[1] = f2b(acc1);
    }
    *(s16x2*)&aggb[(long)c * OS + fo] = o;
}

// ---------------------------------------------------------------------------
// Edge scores from bf16 emb2: one 64-lane wave per query edge
// ---------------------------------------------------------------------------
__global__ void edge_score_b(const short* __restrict__ emb2b, const int* __restrict__ eli,
                             const float* __restrict__ ea, const float* __restrict__ pw,
                             const float* __restrict__ pb, float* __restrict__ scores, int Q) {
    int t = blockIdx.x * 256 + threadIdx.x;
    int e = t >> 6, l = t & 63;
    if (e >= Q) return;
    int s = eli[e], d = eli[Q + e];
    const int f = l * 2;
    s16x2 vs = *(const s16x2*)&emb2b[(long)s * 128 + f];
    s16x2 vd = *(const s16x2*)&emb2b[(long)d * 128 + f];
    float acc = b2f(vs[0]) * pw[f] + b2f(vs[1]) * pw[f + 1]
              + b2f(vd[0]) * pw[128 + f] + b2f(vd[1]) * pw[128 + f + 1];
    if (l < 16) acc += ea[(long)e * 16 + l] * pw[256 + l];
#pragma unroll
    for (int off = 32; off > 0; off >>= 1) acc += __shfl_down(acc, off);
    if (l == 0) scores[e] = acc + pb[0];
}

// ---------------------------------------------------------------------------

extern "C" void kernel_launch(void* const* d_in, const int* in_sizes, int n_in,
                              void* d_out, int out_size, void* d_ws, size_t ws_size,
                              hipStream_t stream) {
    const float* x       = (const float*)d_in[0];
    const int*   ei      = (const int*)d_in[1];
    const int*   eli     = (const int*)d_in[2];
    const float* eattr   = (const float*)d_in[3];
    const float* prev1   = (const float*)d_in[4];
    const float* prev2   = (const float*)d_in[5];
    const float* pre1_W  = (const float*)d_in[6];
    const float* pre1_b  = (const float*)d_in[7];
    const float* pre2_W  = (const float*)d_in[8];
    const float* pre2_b  = (const float*)d_in[9];
    const float* conv1_W = (const float*)d_in[10];
    const float* conv1_b = (const float*)d_in[11];
    const float* conv2_W = (const float*)d_in[12];
    const float* conv2_b = (const float*)d_in[13];
    const float* g1_Wih  = (const float*)d_in[14];
    const float* g1_Whh  = (const float*)d_in[15];
    const float* g1_bih  = (const float*)d_in[16];
    const float* g1_bhh  = (const float*)d_in[17];
    const float* g2_Wih  = (const float*)d_in[18];
    const float* g2_Whh  = (const float*)d_in[19];
    const float* g2_bih  = (const float*)d_in[20];
    const float* g2_bhh  = (const float*)d_in[21];
    const float* post_W  = (const float*)d_in[22];
    const float* post_b  = (const float*)d_in[23];

    float* out    = (float*)d_out;
    float* scores = out;                      // [NQ]
    float* emb1   = out + NQ;                 // [N,256]
    float* emb2   = emb1 + (long)NN * 256;    // [N,128]

    // workspace layout (bytes)
    char* ws = (char*)d_ws;
    const long S256 = MP * 256 * 2;           // 25,624,576
    const long S128 = MP * 128 * 2;           // 12,812,288
    short* R1  = (short*)ws;                          // xb -> G1 -> AP2
    short* R2  = (short*)(ws + S256);                 // h1b -> emb1b
    short* R3  = (short*)(ws + 2 * S256);             // h2b -> hw2b -> emb2b
    short* AP1 = (short*)(ws + 2 * S256 + S128);      // [MP][512]
    short* AP2 = R1;                                  // [MP][256], aliases R1
    char*  wts = ws + 4 * S256 + S128;
    short* pre1T  = (short*)wts;            // [256][256]
    short* pre2T  = pre1T + 256 * 256;      // [128][256]
    short* conv1T = pre2T + 128 * 256;      // [256][128]
    short* conv2T = conv1T + 256 * 128;     // [128][256]
    short* W1g1   = conv2T + 128 * 256;     // [1024][512]
    short* W1g2   = W1g1 + 1024 * 512;      // [512][256]
    float* dinv   = (float*)(W1g2 + 512 * 256);   // [NN]
    int*   cnt    = (int*)(dinv + NN);            // [NN]
    int*   off    = cnt + NN;                     // [NN+1]
    int*   cursor = off + NN + 1;                 // [NN]
    int*   bsum   = cursor + NN;                  // [256]
    int*   srow   = bsum + 256;                   // [NE]
    float* snorm  = (float*)(srow + NE);          // [NE]

    const int* rows = ei;
    const int* cols = ei + NE;

    dim3 blk(256);
    const int NB = (NN + 255) / 256;   // 196

    // --- conversions / weight builds ---
    f2b_rows<<<(MP * 256 + 255) / 256, blk, 0, stream>>>(x, R1, (long)NN * 256, MP * 256);
    wT_b<<<(256 * 256 + 255) / 256, blk, 0, stream>>>(pre1_W, pre1T, 256, 256);
    wT_b<<<(128 * 256 + 255) / 256, blk, 0, stream>>>(pre2_W, pre2T, 256, 128);
    wT_b<<<(256 * 128 + 255) / 256, blk, 0, stream>>>(conv1_W, conv1T, 128, 256);
    wT_b<<<(128 * 256 + 255) / 256, blk, 0, stream>>>(conv2_W, conv2T, 256, 128);
    build_gruW<256><<<(1024 * 512 + 255) / 256, blk, 0, stream>>>(g1_Wih, g1_Whh, W1g1);
    build_gruW<128><<<(512 * 256 + 255) / 256, blk, 0, stream>>>(g2_Wih, g2_Whh, W1g2);

    // --- CSR build (once, reused by both layers) ---
    hipMemsetAsync(cnt, 0, NN * sizeof(int), stream);
    cnt_kernel<<<(NE + 255) / 256, blk, 0, stream>>>(cols, cnt, NE);
    dinv_kernel<<<NB, blk, 0, stream>>>(cnt, dinv, NN);
    scan1<<<NB, blk, 0, stream>>>(cnt, off, bsum, NN);
    scan2<<<1, blk, 0, stream>>>(bsum, NB);
    scan3<<<NB, blk, 0, stream>>>(off, bsum, NN);
    hipMemsetAsync(cursor, 0, NN * sizeof(int), stream);
    fill_csr<<<(NE + 255) / 256, blk, 0, stream>>>(rows, cols, dinv, off, cursor, srow, snorm, NE);

    // --- dense pre-layers ---
    gemm_mfma<1, true><<<dim3(391, 2), blk, 0, stream>>>(R1, pre1T, pre1_b, R2, NN, 256, 256, 256);
    gemm_mfma<1, true><<<dim3(391, 1), blk, 0, stream>>>(R2, pre2T, pre2_b, R3, NN, 128, 256, 128);

    // --- GCN1: aggregate FIRST on 128-dim h2 (raw), then conv1 GEMM ---
    gather_agg<128, false><<<(NN + 3) / 4, blk, 0, stream>>>(R3, off, srow, snorm, dinv, nullptr, R1, NN);
    // conv1: lrelu(G1 @ conv1W + b) -> AP1 left half (stride 512)
    gemm_mfma<1, true><<<dim3(391, 2), blk, 0, stream>>>(R1, conv1T, conv1_b, AP1, NN, 256, 128, 512);
    f2b_strided<<<((long)NN * 256 + 255) / 256, blk, 0, stream>>>(prev1, AP1, 256, (long)NN * 256);

    // --- GRU1 (wide fused, 512 thr) -> emb1 fp32 + emb1b bf16 (R2) ---
    gru_wide<256, true><<<dim3(391, 4), dim3(512), 0, stream>>>(AP1, W1g1, prev1, g1_bih, g1_bhh,
                                                                emb1, R2, NN);

    // --- conv2 ---
    gemm_mfma<0, true><<<dim3(391, 1), blk, 0, stream>>>(R2, conv2T, nullptr, R3, NN, 128, 256, 128);

    // --- GCN2: aggregate (fused bias+lrelu) -> AP2 left half ---
    gather_agg<256, true><<<(NN + 3) / 4, blk, 0, stream>>>(R3, off, srow, snorm, dinv, conv2_b, AP2, NN);
    f2b_strided<<<((long)NN * 128 + 255) / 256, blk, 0, stream>>>(prev2, AP2, 128, (long)NN * 128);

    // --- GRU2 (wide fused) -> emb2 fp32 + emb2b bf16 (R3) ---
    gru_wide<128, true><<<dim3(391, 2), dim3(512), 0, stream>>>(AP2, W1g2, prev2, g2_bih, g2_bhh,
                                                                emb2, R3, NN);

    // --- edge scores (bf16 gather) ---
    edge_score_b<<<NQ / 4, blk, 0, stream>>>(R3, eli, eattr, post_W, post_b, scores, NQ);
}

// Round 6
// 509.113 us; speedup vs baseline: 1.1633x; 1.1484x over previous
//
#include <hip/hip_runtime.h>
#include <hip/hip_bf16.h>

#define DEVFN __device__ __forceinline__

constexpr int NN = 50000;
constexpr int NE = 800000;
constexpr int NQ = 200000;
constexpr long MP = 50048;   // NN padded to multiple of 128

typedef __attribute__((ext_vector_type(8))) short bf16x8;
typedef __attribute__((ext_vector_type(2))) short s16x2;
typedef __attribute__((ext_vector_type(4))) float f32x4;
typedef __attribute__((address_space(1))) const void gv_t;
typedef __attribute__((address_space(3))) void lv_t;

DEVFN float lrelu(float x) { return x > 0.f ? x : 0.01f * x; }
DEVFN float sigmoidf(float x) { return 1.f / (1.f + __expf(-x)); }

DEVFN short f2b(float v) {
    __hip_bfloat16 h = __float2bfloat16(v);
    return *reinterpret_cast<short*>(&h);
}
DEVFN float b2f(short s) {
    union { unsigned u; float f; } z;
    z.u = ((unsigned)(unsigned short)s) << 16;
    return z.f;
}
DEVFN void gld16(const void* g, void* l) {
    __builtin_amdgcn_global_load_lds((gv_t*)g, (lv_t*)l, 16, 0, 0);
}

// ---------------------------------------------------------------------------
// GRU interleaved-weight value: W1 [4H][2H]; row n' = g16*64 + chunk*16 + cl;
// real col c = g16*16+cl; chunks: r, z, inn (k<H only), hn (k>=H only).
// ---------------------------------------------------------------------------
template <int H>
DEVFN float gruw_val(const float* Wih, const float* Whh, int i) {
    constexpr int K2 = 2 * H, W3 = 3 * H;
    int np = i / K2, k = i % K2;
    int g16 = np >> 6, chunk = (np >> 4) & 3, cl = np & 15;
    int c = g16 * 16 + cl;
    if (chunk == 0) return (k < H) ? Wih[(long)k * W3 + c] : Whh[(long)(k - H) * W3 + c];
    if (chunk == 1) return (k < H) ? Wih[(long)k * W3 + H + c] : Whh[(long)(k - H) * W3 + H + c];
    if (chunk == 2) return (k < H) ? Wih[(long)k * W3 + 2 * H + c] : 0.f;
    return (k < H) ? 0.f : Whh[(long)(k - H) * W3 + 2 * H + c];
}

// ---------------------------------------------------------------------------
// One mega prep kernel: xb, prev1->AP1 right half, 4 transposed weights,
// 2 interleaved GRU weights. Flat range dispatch.
// ---------------------------------------------------------------------------
__global__ void prep_all(const float* __restrict__ x, const float* __restrict__ prev1,
                         const float* __restrict__ pre1W, const float* __restrict__ pre2W,
                         const float* __restrict__ conv1W, const float* __restrict__ conv2W,
                         const float* __restrict__ g1ih, const float* __restrict__ g1hh,
                         const float* __restrict__ g2ih, const float* __restrict__ g2hh,
                         short* __restrict__ xb, short* __restrict__ AP1,
                         short* __restrict__ pre1T, short* __restrict__ pre2T,
                         short* __restrict__ conv1T, short* __restrict__ conv2T,
                         short* __restrict__ W1g1, short* __restrict__ W1g2) {
    long i = (long)blockIdx.x * 256 + threadIdx.x;
    if (i < MP * 256) {                                   // xb (zero-padded)
        xb[i] = (i < (long)NN * 256) ? f2b(x[i]) : (short)0;
        return;
    }
    i -= MP * 256;
    if (i < (long)NN * 256) {                             // prev1 -> AP1 right half
        long r = i >> 8; int c = (int)(i & 255);
        AP1[r * 512 + 256 + c] = f2b(prev1[i]);
        return;
    }
    i -= (long)NN * 256;
    if (i < 65536) { int ii = (int)i, n = ii >> 8, k = ii & 255; pre1T[ii] = f2b(pre1W[k * 256 + n]); return; }
    i -= 65536;
    if (i < 32768) { int ii = (int)i, n = ii >> 8, k = ii & 255; pre2T[ii] = f2b(pre2W[k * 128 + n]); return; }
    i -= 32768;
    if (i < 32768) { int ii = (int)i, n = ii >> 7, k = ii & 127; conv1T[ii] = f2b(conv1W[k * 256 + n]); return; }
    i -= 32768;
    if (i < 32768) { int ii = (int)i, n = ii >> 8, k = ii & 255; conv2T[ii] = f2b(conv2W[k * 128 + n]); return; }
    i -= 32768;
    if (i < 524288) { W1g1[i] = f2b(gruw_val<256>(g1ih, g1hh, (int)i)); return; }
    i -= 524288;
    if (i < 131072) W1g2[i] = f2b(gruw_val<128>(g2ih, g2hh, (int)i));
}

// prev2 -> AP2 right half (must run after R1's G1 role ends)
__global__ void f2b_strided(const float* __restrict__ in, short* __restrict__ out,
                            int H, long n) {
    long i = (long)blockIdx.x * 256 + threadIdx.x;
    if (i >= n) return;
    long r = i / H;
    int c = i % H;
    out[r * 2 * H + H + c] = f2b(in[i]);
}

// ---------------------------------------------------------------------------
// bf16 MFMA GEMM, 2-phase dbuf + XOR slot swizzle:
// C = epi(A[Mpad][K] @ Bt[Nt][K]^T + bias); BM=BN=128, BK=32, 4 waves.
// bf16 C written with row stride obS.
// ---------------------------------------------------------------------------
template <int EPI>
__global__ __launch_bounds__(256)
void gemm_mfma(const short* __restrict__ A, const short* __restrict__ Bt,
               const float* __restrict__ bias,
               short* __restrict__ Cb, int Nt, int K, int obS) {
    __shared__ alignas(16) short As[2][4096];
    __shared__ alignas(16) short Bs[2][4096];
    const int tid = threadIdx.x;
    const int lane = tid & 63, w = tid >> 6;
    const int wr = w >> 1, wc = w & 1;
    const long row0 = (long)blockIdx.x * 128;
    const long col0 = (long)blockIdx.y * 128;

    f32x4 acc[4][4] = {};

    const int kcs = ((tid & 3) ^ ((tid >> 3) & 3)) * 8;  // pre-swizzled global slot
    const short* gA = A + (row0 + (tid >> 2)) * (long)K + kcs;
    const short* gB = Bt + (col0 + (tid >> 2)) * (long)K + kcs;
    const long half = 64 * (long)K;

    auto stage = [&](int b, int k0) {
        gld16(gA + k0, &As[b][tid * 8]);
        gld16(gA + half + k0, &As[b][2048 + tid * 8]);
        gld16(gB + k0, &Bs[b][tid * 8]);
        gld16(gB + half + k0, &Bs[b][2048 + tid * 8]);
    };

    stage(0, 0);
    int cur = 0;
    const int l15 = lane & 15;
    const int kq = ((lane >> 4) ^ ((l15 >> 1) & 3)) * 8;  // swizzled slot on read
    for (int k0 = 0; k0 < K; k0 += 32) {
        __syncthreads();
        if (k0 + 32 < K) stage(cur ^ 1, k0 + 32);
        bf16x8 af[4], bfr[4];
#pragma unroll
        for (int i = 0; i < 4; ++i)
            af[i] = *(const bf16x8*)&As[cur][(wr * 64 + i * 16 + l15) * 32 + kq];
#pragma unroll
        for (int j = 0; j < 4; ++j)
            bfr[j] = *(const bf16x8*)&Bs[cur][(wc * 64 + j * 16 + l15) * 32 + kq];
#pragma unroll
        for (int i = 0; i < 4; ++i)
#pragma unroll
            for (int j = 0; j < 4; ++j)
                acc[i][j] = __builtin_amdgcn_mfma_f32_16x16x32_bf16(af[i], bfr[j], acc[i][j], 0, 0, 0);
        cur ^= 1;
    }

    const int cr = (lane >> 4) * 4, cc = lane & 15;
#pragma unroll
    for (int i = 0; i < 4; ++i) {
#pragma unroll
        for (int j = 0; j < 4; ++j) {
            const long col = col0 + wc * 64 + j * 16 + cc;
            float bv = (EPI == 1) ? bias[col] : 0.f;
#pragma unroll
            for (int r = 0; r < 4; ++r) {
                const long row = row0 + wr * 64 + i * 16 + cr + r;
                float v = acc[i][j][r];
                if (EPI == 1) v = lrelu(v + bv);
                Cb[row * obS + col] = f2b(v);
            }
        }
    }
}

// ---------------------------------------------------------------------------
// Wide fused GRU, 256 threads, tile 128 rows x 128 n'-cols, 4 waves (2x2),
// with K-split: frag/chunk 2 (inn) only k<H, frag/chunk 3 (hn) only k>=H.
// B-staging waves 2/3 skip the half they don't own. 12 MFMA + 7 ds_read/step.
// ---------------------------------------------------------------------------
template <int H, bool WRITEB>
__global__ __launch_bounds__(256)
void gru_wide(const short* __restrict__ AP, const short* __restrict__ W1,
              const float* __restrict__ prevf,
              const float* __restrict__ bih, const float* __restrict__ bhh,
              float* __restrict__ outF, short* __restrict__ outB, int M) {
    constexpr int K2 = 2 * H;
    __shared__ alignas(16) short As[2][4096];
    __shared__ alignas(16) short Bs[2][4096];
    const int tid = threadIdx.x;
    const int lane = tid & 63, w = tid >> 6;
    const int wr = w >> 1, wc = w & 1;
    const long row0 = (long)blockIdx.x * 128;
    const long col0 = (long)blockIdx.y * 128;   // n' space

    f32x4 acc[4][4] = {};

    const int kcs = ((tid & 3) ^ ((tid >> 3) & 3)) * 8;
    const short* gA = AP + (row0 + (tid >> 2)) * (long)K2 + kcs;
    const short* gB = W1 + (col0 + (tid >> 2)) * (long)K2 + kcs;
    const long half = 64 * (long)K2;

    // B-rows staged by thread t: np = t>>2 and 64+(t>>2); chunk((t>>2)) maps
    // wave 2 -> chunk 2 rows, wave 3 -> chunk 3 rows (both gld16s).
    auto stage = [&](int b, int k0) {
        const bool lo = (k0 < H);
        gld16(gA + k0, &As[b][tid * 8]);
        gld16(gA + half + k0, &As[b][2048 + tid * 8]);
        const bool bskip = (w == 2 && !lo) || (w == 3 && lo);
        if (!bskip) {
            gld16(gB + k0, &Bs[b][tid * 8]);
            gld16(gB + half + k0, &Bs[b][2048 + tid * 8]);
        }
    };

    stage(0, 0);
    int cur = 0;
    const int l15 = lane & 15;
    const int kq = ((lane >> 4) ^ ((l15 >> 1) & 3)) * 8;
    for (int k0 = 0; k0 < K2; k0 += 32) {
        const bool lo = (k0 < H);
        __syncthreads();
        if (k0 + 32 < K2) stage(cur ^ 1, k0 + 32);
        bf16x8 af[4], bfr[4];
#pragma unroll
        for (int i = 0; i < 4; ++i)
            af[i] = *(const bf16x8*)&As[cur][(wr * 64 + i * 16 + l15) * 32 + kq];
#pragma unroll
        for (int j = 0; j < 4; ++j) {
            if ((j == 2 && !lo) || (j == 3 && lo)) continue;
            bfr[j] = *(const bf16x8*)&Bs[cur][(wc * 64 + j * 16 + l15) * 32 + kq];
        }
#pragma unroll
        for (int i = 0; i < 4; ++i)
#pragma unroll
            for (int j = 0; j < 4; ++j) {
                if ((j == 2 && !lo) || (j == 3 && lo)) continue;
                acc[i][j] = __builtin_amdgcn_mfma_f32_16x16x32_bf16(af[i], bfr[j], acc[i][j], 0, 0, 0);
            }
        cur ^= 1;
    }

    // gating epilogue: frag j = chunk j (0=r, 1=z, 2=inn, 3=hn)
    const int cr = (lane >> 4) * 4;
    const int c = (int)blockIdx.y * 32 + wc * 16 + (lane & 15);  // real col
    const float bsr = bih[c] + bhh[c];
    const float bsz = bih[H + c] + bhh[H + c];
    const float bin = bih[2 * H + c];
    const float bhn = bhh[2 * H + c];
#pragma unroll
    for (int i = 0; i < 4; ++i) {
#pragma unroll
        for (int r = 0; r < 4; ++r) {
            const long row = row0 + wr * 64 + i * 16 + cr + r;
            if (row >= M) continue;
            float rg = sigmoidf(acc[i][0][r] + bsr);
            float zg = sigmoidf(acc[i][1][r] + bsz);
            float ng = tanhf(acc[i][2][r] + bin + rg * (acc[i][3][r] + bhn));
            float o = (1.f - zg) * ng + zg * prevf[row * (long)H + c];
            outF[row * (long)H + c] = o;
            if (WRITEB) outB[row * (long)H + c] = f2b(o);
        }
    }
}

// ---------------------------------------------------------------------------
// CSR build: count -> scan(+dinv) -> fill
// ---------------------------------------------------------------------------
__global__ void cnt_kernel(const int* __restrict__ cols, int* __restrict__ cnt, int E) {
    int e = blockIdx.x * 256 + threadIdx.x;
    if (e < E) atomicAdd(&cnt[cols[e]], 1);
}

__global__ void scan1(const int* __restrict__ cnt, int* __restrict__ off,
                      int* __restrict__ bsum, float* __restrict__ dinv, int n) {
    __shared__ int sm[256];
    int i = blockIdx.x * 256 + threadIdx.x;
    int v = (i < n) ? cnt[i] : 0;
    if (i < n) dinv[i] = rsqrtf((float)v + 1.0f);   // +1 self-loop
    sm[threadIdx.x] = v;
    __syncthreads();
    for (int s = 1; s < 256; s <<= 1) {
        int t = (threadIdx.x >= s) ? sm[threadIdx.x - s] : 0;
        __syncthreads();
        sm[threadIdx.x] += t;
        __syncthreads();
    }
    if (i < n) off[i + 1] = sm[threadIdx.x];
    if (threadIdx.x == 255) bsum[blockIdx.x] = sm[255];
}

__global__ void scan2(int* __restrict__ bsum, int nb) {
    __shared__ int sm[256];
    int v = (threadIdx.x < nb) ? bsum[threadIdx.x] : 0;
    sm[threadIdx.x] = v;
    __syncthreads();
    for (int s = 1; s < 256; s <<= 1) {
        int t = (threadIdx.x >= s) ? sm[threadIdx.x - s] : 0;
        __syncthreads();
        sm[threadIdx.x] += t;
        __syncthreads();
    }
    if (threadIdx.x < nb) bsum[threadIdx.x] = sm[threadIdx.x] - v;  // exclusive
}

__global__ void scan3(int* __restrict__ off, const int* __restrict__ bsum, int n) {
    int i = blockIdx.x * 256 + threadIdx.x;
    if (i < n) off[i + 1] += bsum[blockIdx.x];
    if (i == 0) off[0] = 0;
}

__global__ void fill_csr(const int* __restrict__ rows, const int* __restrict__ cols,
                         const float* __restrict__ dinv, const int* __restrict__ off,
                         int* __restrict__ cursor, int* __restrict__ srow,
                         float* __restrict__ snorm, int E) {
    int e = blockIdx.x * 256 + threadIdx.x;
    if (e >= E) return;
    int r = rows[e], c = cols[e];
    int p = off[c] + atomicAdd(&cursor[c], 1);
    srow[p] = r;
    snorm[p] = dinv[r] * dinv[c];
}

// ---------------------------------------------------------------------------
// Gather-aggregate over H=128 feats, one wave per dest node, 4x unrolled.
// Output row stride OS; EPI adds bias+lrelu.
// ---------------------------------------------------------------------------
template <int OS, bool EPI>
__global__ __launch_bounds__(256)
void gather_agg(const short* __restrict__ hwb, const int* __restrict__ off,
                const int* __restrict__ srow, const float* __restrict__ snorm,
                const float* __restrict__ dinv, const float* __restrict__ bias,
                short* __restrict__ aggb, int n) {
    constexpr int H = 128;
    int t = blockIdx.x * 256 + threadIdx.x;
    int c = t >> 6, l = t & 63;
    if (c >= n) return;
    const int fo = l * 2;
    float acc0, acc1;
    {
        float dd = dinv[c] * dinv[c];
        s16x2 v = *(const s16x2*)&hwb[(long)c * H + fo];
        acc0 = b2f(v[0]) * dd;
        acc1 = b2f(v[1]) * dd;
    }
    int e = off[c];
    const int e1 = off[c + 1];
    for (; e + 3 < e1; e += 4) {
        int r0 = srow[e], r1 = srow[e + 1], r2 = srow[e + 2], r3 = srow[e + 3];
        float n0 = snorm[e], n1 = snorm[e + 1], n2 = snorm[e + 2], n3 = snorm[e + 3];
        s16x2 v0 = *(const s16x2*)&hwb[(long)r0 * H + fo];
        s16x2 v1 = *(const s16x2*)&hwb[(long)r1 * H + fo];
        s16x2 v2 = *(const s16x2*)&hwb[(long)r2 * H + fo];
        s16x2 v3 = *(const s16x2*)&hwb[(long)r3 * H + fo];
        acc0 += b2f(v0[0]) * n0 + b2f(v1[0]) * n1 + b2f(v2[0]) * n2 + b2f(v3[0]) * n3;
        acc1 += b2f(v0[1]) * n0 + b2f(v1[1]) * n1 + b2f(v2[1]) * n2 + b2f(v3[1]) * n3;
    }
    for (; e < e1; ++e) {
        int r0 = srow[e];
        float n0 = snorm[e];
        s16x2 v0 = *(const s16x2*)&hwb[(long)r0 * H + fo];
        acc0 += b2f(v0[0]) * n0;
        acc1 += b2f(v0[1]) * n0;
    }
    s16x2 o;
    if (EPI) {
        o[0] = f2b(lrelu(acc0 + bias[fo]));
        o[1] = f2b(lrelu(acc1 + bias[fo + 1]));
    } else {
        o[0] = f2b(acc0);
        o[1] = f2b(acc1);
    }
    *(s16x2*)&aggb[(long)c * OS + fo] = o;
}

// ---------------------------------------------------------------------------
// Edge scores from bf16 emb2: one 64-lane wave per query edge
// ---------------------------------------------------------------------------
__global__ void edge_score_b(const short* __restrict__ emb2b, const int* __restrict__ eli,
                             const float* __restrict__ ea, const float* __restrict__ pw,
                             const float* __restrict__ pb, float* __restrict__ scores, int Q) {
    int t = blockIdx.x * 256 + threadIdx.x;
    int e = t >> 6, l = t & 63;
    if (e >= Q) return;
    int s = eli[e], d = eli[Q + e];
    const int f = l * 2;
    s16x2 vs = *(const s16x2*)&emb2b[(long)s * 128 + f];
    s16x2 vd = *(const s16x2*)&emb2b[(long)d * 128 + f];
    float acc = b2f(vs[0]) * pw[f] + b2f(vs[1]) * pw[f + 1]
              + b2f(vd[0]) * pw[128 + f] + b2f(vd[1]) * pw[128 + f + 1];
    if (l < 16) acc += ea[(long)e * 16 + l] * pw[256 + l];
#pragma unroll
    for (int off = 32; off > 0; off >>= 1) acc += __shfl_down(acc, off);
    if (l == 0) scores[e] = acc + pb[0];
}

// ---------------------------------------------------------------------------

extern "C" void kernel_launch(void* const* d_in, const int* in_sizes, int n_in,
                              void* d_out, int out_size, void* d_ws, size_t ws_size,
                              hipStream_t stream) {
    const float* x       = (const float*)d_in[0];
    const int*   ei      = (const int*)d_in[1];
    const int*   eli     = (const int*)d_in[2];
    const float* eattr   = (const float*)d_in[3];
    const float* prev1   = (const float*)d_in[4];
    const float* prev2   = (const float*)d_in[5];
    const float* pre1_W  = (const float*)d_in[6];
    const float* pre1_b  = (const float*)d_in[7];
    const float* pre2_W  = (const float*)d_in[8];
    const float* pre2_b  = (const float*)d_in[9];
    const float* conv1_W = (const float*)d_in[10];
    const float* conv1_b = (const float*)d_in[11];
    const float* conv2_W = (const float*)d_in[12];
    const float* conv2_b = (const float*)d_in[13];
    const float* g1_Wih  = (const float*)d_in[14];
    const float* g1_Whh  = (const float*)d_in[15];
    const float* g1_bih  = (const float*)d_in[16];
    const float* g1_bhh  = (const float*)d_in[17];
    const float* g2_Wih  = (const float*)d_in[18];
    const float* g2_Whh  = (const float*)d_in[19];
    const float* g2_bih  = (const float*)d_in[20];
    const float* g2_bhh  = (const float*)d_in[21];
    const float* post_W  = (const float*)d_in[22];
    const float* post_b  = (const float*)d_in[23];

    float* out    = (float*)d_out;
    float* scores = out;                      // [NQ]
    float* emb1   = out + NQ;                 // [N,256]
    float* emb2   = emb1 + (long)NN * 256;    // [N,128]

    // workspace layout (bytes)
    char* ws = (char*)d_ws;
    const long S256 = MP * 256 * 2;           // 25,624,576
    const long S128 = MP * 128 * 2;           // 12,812,288
    short* R1  = (short*)ws;                          // xb -> G1 -> AP2
    short* R2  = (short*)(ws + S256);                 // h1b -> emb1b
    short* R3  = (short*)(ws + 2 * S256);             // h2b -> hw2b -> emb2b
    short* AP1 = (short*)(ws + 2 * S256 + S128);      // [MP][512]
    short* AP2 = R1;                                  // [MP][256], aliases R1
    char*  wts = ws + 4 * S256 + S128;
    short* pre1T  = (short*)wts;            // [256][256]
    short* pre2T  = pre1T + 256 * 256;      // [128][256]
    short* conv1T = pre2T + 128 * 256;      // [256][128]
    short* conv2T = conv1T + 256 * 128;     // [128][256]
    short* W1g1   = conv2T + 128 * 256;     // [1024][512]
    short* W1g2   = W1g1 + 1024 * 512;      // [512][256]
    float* dinv   = (float*)(W1g2 + 512 * 256);   // [NN]
    int*   cnt    = (int*)(dinv + NN);            // [NN]   (cnt+cursor adjacent
    int*   cursor = cnt + NN;                     // [NN]    -> single memset)
    int*   off    = cursor + NN;                  // [NN+1]
    int*   bsum   = off + NN + 1;                 // [256]
    int*   srow   = bsum + 256;                   // [NE]
    float* snorm  = (float*)(srow + NE);          // [NE]

    const int* rows = ei;
    const int* cols = ei + NE;

    dim3 blk(256);
    const int NB = (NN + 255) / 256;   // 196

    // --- single prep kernel: xb, prev1->AP1, all weight transforms ---
    const long PREP = MP * 256 + (long)NN * 256 + 65536 + 3 * 32768 + 524288 + 131072;
    prep_all<<<(int)((PREP + 255) / 256), blk, 0, stream>>>(
        x, prev1, pre1_W, pre2_W, conv1_W, conv2_W,
        g1_Wih, g1_Whh, g2_Wih, g2_Whh,
        R1, AP1, pre1T, pre2T, conv1T, conv2T, W1g1, W1g2);

    // --- CSR build (once, reused by both layers) ---
    hipMemsetAsync(cnt, 0, 2 * NN * sizeof(int), stream);   // cnt + cursor
    cnt_kernel<<<(NE + 255) / 256, blk, 0, stream>>>(cols, cnt, NE);
    scan1<<<NB, blk, 0, stream>>>(cnt, off, bsum, dinv, NN);
    scan2<<<1, blk, 0, stream>>>(bsum, NB);
    scan3<<<NB, blk, 0, stream>>>(off, bsum, NN);
    fill_csr<<<(NE + 255) / 256, blk, 0, stream>>>(rows, cols, dinv, off, cursor, srow, snorm, NE);

    // --- dense pre-layers ---
    gemm_mfma<1><<<dim3(391, 2), blk, 0, stream>>>(R1, pre1T, pre1_b, R2, 256, 256, 256);
    gemm_mfma<1><<<dim3(391, 1), blk, 0, stream>>>(R2, pre2T, pre2_b, R3, 128, 256, 128);

    // --- GCN1: aggregate on 128-dim h2 (raw), then conv1 GEMM -> AP1 left ---
    gather_agg<128, false><<<(NN + 3) / 4, blk, 0, stream>>>(R3, off, srow, snorm, dinv, nullptr, R1, NN);
    gemm_mfma<1><<<dim3(391, 2), blk, 0, stream>>>(R1, conv1T, conv1_b, AP1, 256, 128, 512);

    // --- GRU1 (wide fused, K-split) -> emb1 fp32 + emb1b bf16 (R2) ---
    gru_wide<256, true><<<dim3(391, 8), blk, 0, stream>>>(AP1, W1g1, prev1, g1_bih, g1_bhh,
                                                          emb1, R2, NN);

    // --- prev2 -> AP2 right half (R1's G1 role ended at conv1) ---
    f2b_strided<<<(int)(((long)NN * 128 + 255) / 256), blk, 0, stream>>>(prev2, AP2, 128, (long)NN * 128);

    // --- conv2 ---
    gemm_mfma<0><<<dim3(391, 1), blk, 0, stream>>>(R2, conv2T, nullptr, R3, 128, 256, 128);

    // --- GCN2: aggregate (fused bias+lrelu) -> AP2 left half ---
    gather_agg<256, true><<<(NN + 3) / 4, blk, 0, stream>>>(R3, off, srow, snorm, dinv, conv2_b, AP2, NN);

    // --- GRU2 (wide fused, K-split) -> emb2 fp32 + emb2b bf16 (R3) ---
    gru_wide<128, true><<<dim3(391, 4), blk, 0, stream>>>(AP2, W1g2, prev2, g2_bih, g2_bhh,
                                                          emb2, R3, NN);

    // --- edge scores (bf16 gather) ---
    edge_score_b<<<NQ / 4, blk, 0, stream>>>(R3, eli, eattr, post_W, post_b, scores, NQ);
}

// Round 7
// 480.876 us; speedup vs baseline: 1.2317x; 1.0587x over previous
//
#include <hip/hip_runtime.h>
#include <hip/hip_bf16.h>

#define DEVFN __device__ __forceinline__

constexpr int NN = 50000;
constexpr int NE = 800000;
constexpr int NQ = 200000;
constexpr long MP = 50048;   // NN padded to multiple of 128

typedef __attribute__((ext_vector_type(8))) short bf16x8;
typedef __attribute__((ext_vector_type(2))) short s16x2;
typedef __attribute__((ext_vector_type(4))) float f32x4;
typedef __attribute__((address_space(1))) const void gv_t;
typedef __attribute__((address_space(3))) void lv_t;

DEVFN float lrelu(float x) { return x > 0.f ? x : 0.01f * x; }
DEVFN float sigmoidf(float x) { return 1.f / (1.f + __expf(-x)); }

DEVFN short f2b(float v) {
    __hip_bfloat16 h = __float2bfloat16(v);
    return *reinterpret_cast<short*>(&h);
}
DEVFN float b2f(short s) {
    union { unsigned u; float f; } z;
    z.u = ((unsigned)(unsigned short)s) << 16;
    return z.f;
}
DEVFN void gld16(const void* g, void* l) {
    __builtin_amdgcn_global_load_lds((gv_t*)g, (lv_t*)l, 16, 0, 0);
}

// ---------------------------------------------------------------------------
// Bijective XCD-chunked swizzle (m204): linear dispatch id -> work id such
// that each XCD gets a CONTIGUOUS work range; work ordered col-strip-fastest
// so one XCD sweeps all column strips of a row band (A-tile L2 reuse).
// ---------------------------------------------------------------------------
DEVFN void swz_rc(int d, int nwg, int NC, int& rw, int& cs) {
    int q0 = nwg >> 3, rr = nwg & 7;
    int xcd = d & 7, idx = d >> 3;
    int w = (xcd < rr ? xcd * (q0 + 1) : rr * (q0 + 1) + (xcd - rr) * q0) + idx;
    rw = w / NC;
    cs = w - rw * NC;
}

// ---------------------------------------------------------------------------
// GRU interleaved-weight value: W1 [4H][2H]; row n' = g16*64 + chunk*16 + cl;
// real col c = g16*16+cl; chunks: r, z, inn (k<H only), hn (k>=H only).
// ---------------------------------------------------------------------------
template <int H>
DEVFN float gruw_val(const float* Wih, const float* Whh, int i) {
    constexpr int K2 = 2 * H, W3 = 3 * H;
    int np = i / K2, k = i % K2;
    int g16 = np >> 6, chunk = (np >> 4) & 3, cl = np & 15;
    int c = g16 * 16 + cl;
    if (chunk == 0) return (k < H) ? Wih[(long)k * W3 + c] : Whh[(long)(k - H) * W3 + c];
    if (chunk == 1) return (k < H) ? Wih[(long)k * W3 + H + c] : Whh[(long)(k - H) * W3 + H + c];
    if (chunk == 2) return (k < H) ? Wih[(long)k * W3 + 2 * H + c] : 0.f;
    return (k < H) ? 0.f : Whh[(long)(k - H) * W3 + 2 * H + c];
}

// ---------------------------------------------------------------------------
// One mega prep kernel: xb, prev1->AP1 right half, 4 transposed weights,
// 2 interleaved GRU weights. Flat range dispatch.
// ---------------------------------------------------------------------------
__global__ void prep_all(const float* __restrict__ x, const float* __restrict__ prev1,
                         const float* __restrict__ pre1W, const float* __restrict__ pre2W,
                         const float* __restrict__ conv1W, const float* __restrict__ conv2W,
                         const float* __restrict__ g1ih, const float* __restrict__ g1hh,
                         const float* __restrict__ g2ih, const float* __restrict__ g2hh,
                         short* __restrict__ xb, short* __restrict__ AP1,
                         short* __restrict__ pre1T, short* __restrict__ pre2T,
                         short* __restrict__ conv1T, short* __restrict__ conv2T,
                         short* __restrict__ W1g1, short* __restrict__ W1g2) {
    long i = (long)blockIdx.x * 256 + threadIdx.x;
    if (i < MP * 256) {                                   // xb (zero-padded)
        xb[i] = (i < (long)NN * 256) ? f2b(x[i]) : (short)0;
        return;
    }
    i -= MP * 256;
    if (i < (long)NN * 256) {                             // prev1 -> AP1 right half
        long r = i >> 8; int c = (int)(i & 255);
        AP1[r * 512 + 256 + c] = f2b(prev1[i]);
        return;
    }
    i -= (long)NN * 256;
    if (i < 65536) { int ii = (int)i, n = ii >> 8, k = ii & 255; pre1T[ii] = f2b(pre1W[k * 256 + n]); return; }
    i -= 65536;
    if (i < 32768) { int ii = (int)i, n = ii >> 8, k = ii & 255; pre2T[ii] = f2b(pre2W[k * 128 + n]); return; }
    i -= 32768;
    if (i < 32768) { int ii = (int)i, n = ii >> 7, k = ii & 127; conv1T[ii] = f2b(conv1W[k * 256 + n]); return; }
    i -= 32768;
    if (i < 32768) { int ii = (int)i, n = ii >> 8, k = ii & 255; conv2T[ii] = f2b(conv2W[k * 128 + n]); return; }
    i -= 32768;
    if (i < 524288) { W1g1[i] = f2b(gruw_val<256>(g1ih, g1hh, (int)i)); return; }
    i -= 524288;
    if (i < 131072) W1g2[i] = f2b(gruw_val<128>(g2ih, g2hh, (int)i));
}

// prev2 -> AP2 right half (must run after R1's G1 role ends)
__global__ void f2b_strided(const float* __restrict__ in, short* __restrict__ out,
                            int H, long n) {
    long i = (long)blockIdx.x * 256 + threadIdx.x;
    if (i >= n) return;
    long r = i / H;
    int c = i % H;
    out[r * 2 * H + H + c] = f2b(in[i]);
}

// ---------------------------------------------------------------------------
// bf16 MFMA GEMM, 2-phase dbuf + XOR slot swizzle + XCD-chunked block swizzle.
// C = epi(A[Mpad][K] @ Bt[Nt][K]^T + bias); BM=BN=128, BK=32, 4 waves.
// 1-D grid of nwg = 391*NC blocks; bf16 C written with row stride obS.
// ---------------------------------------------------------------------------
template <int EPI>
__global__ __launch_bounds__(256)
void gemm_mfma(const short* __restrict__ A, const short* __restrict__ Bt,
               const float* __restrict__ bias,
               short* __restrict__ Cb, int K, int obS, int NC, int nwg) {
    __shared__ alignas(16) short As[2][4096];
    __shared__ alignas(16) short Bs[2][4096];
    const int tid = threadIdx.x;
    const int lane = tid & 63, w = tid >> 6;
    const int wr = w >> 1, wc = w & 1;
    int rw, cs;
    swz_rc(blockIdx.x, nwg, NC, rw, cs);
    const long row0 = (long)rw * 128;
    const long col0 = (long)cs * 128;

    f32x4 acc[4][4] = {};

    const int kcs = ((tid & 3) ^ ((tid >> 3) & 3)) * 8;  // pre-swizzled global slot
    const short* gA = A + (row0 + (tid >> 2)) * (long)K + kcs;
    const short* gB = Bt + (col0 + (tid >> 2)) * (long)K + kcs;
    const long half = 64 * (long)K;

    auto stage = [&](int b, int k0) {
        gld16(gA + k0, &As[b][tid * 8]);
        gld16(gA + half + k0, &As[b][2048 + tid * 8]);
        gld16(gB + k0, &Bs[b][tid * 8]);
        gld16(gB + half + k0, &Bs[b][2048 + tid * 8]);
    };

    stage(0, 0);
    int cur = 0;
    const int l15 = lane & 15;
    const int kq = ((lane >> 4) ^ ((l15 >> 1) & 3)) * 8;  // swizzled slot on read
    for (int k0 = 0; k0 < K; k0 += 32) {
        __syncthreads();
        if (k0 + 32 < K) stage(cur ^ 1, k0 + 32);
        bf16x8 af[4], bfr[4];
#pragma unroll
        for (int i = 0; i < 4; ++i)
            af[i] = *(const bf16x8*)&As[cur][(wr * 64 + i * 16 + l15) * 32 + kq];
#pragma unroll
        for (int j = 0; j < 4; ++j)
            bfr[j] = *(const bf16x8*)&Bs[cur][(wc * 64 + j * 16 + l15) * 32 + kq];
#pragma unroll
        for (int i = 0; i < 4; ++i)
#pragma unroll
            for (int j = 0; j < 4; ++j)
                acc[i][j] = __builtin_amdgcn_mfma_f32_16x16x32_bf16(af[i], bfr[j], acc[i][j], 0, 0, 0);
        cur ^= 1;
    }

    const int cr = (lane >> 4) * 4, cc = lane & 15;
#pragma unroll
    for (int i = 0; i < 4; ++i) {
#pragma unroll
        for (int j = 0; j < 4; ++j) {
            const long col = col0 + wc * 64 + j * 16 + cc;
            float bv = (EPI == 1) ? bias[col] : 0.f;
#pragma unroll
            for (int r = 0; r < 4; ++r) {
                const long row = row0 + wr * 64 + i * 16 + cr + r;
                float v = acc[i][j][r];
                if (EPI == 1) v = lrelu(v + bv);
                Cb[row * obS + col] = f2b(v);
            }
        }
    }
}

// ---------------------------------------------------------------------------
// Wide fused GRU, 256 threads, tile 128 rows x 128 n'-cols, 4 waves (2x2),
// K-split (chunk 2 only k<H, chunk 3 only k>=H) + XCD-chunked block swizzle.
// ---------------------------------------------------------------------------
template <int H, bool WRITEB>
__global__ __launch_bounds__(256)
void gru_wide(const short* __restrict__ AP, const short* __restrict__ W1,
              const float* __restrict__ prevf,
              const float* __restrict__ bih, const float* __restrict__ bhh,
              float* __restrict__ outF, short* __restrict__ outB, int M,
              int NC, int nwg) {
    constexpr int K2 = 2 * H;
    __shared__ alignas(16) short As[2][4096];
    __shared__ alignas(16) short Bs[2][4096];
    const int tid = threadIdx.x;
    const int lane = tid & 63, w = tid >> 6;
    const int wr = w >> 1, wc = w & 1;
    int rw, cs;
    swz_rc(blockIdx.x, nwg, NC, rw, cs);
    const long row0 = (long)rw * 128;
    const long col0 = (long)cs * 128;   // n' space

    f32x4 acc[4][4] = {};

    const int kcs = ((tid & 3) ^ ((tid >> 3) & 3)) * 8;
    const short* gA = AP + (row0 + (tid >> 2)) * (long)K2 + kcs;
    const short* gB = W1 + (col0 + (tid >> 2)) * (long)K2 + kcs;
    const long half = 64 * (long)K2;

    auto stage = [&](int b, int k0) {
        const bool lo = (k0 < H);
        gld16(gA + k0, &As[b][tid * 8]);
        gld16(gA + half + k0, &As[b][2048 + tid * 8]);
        const bool bskip = (w == 2 && !lo) || (w == 3 && lo);
        if (!bskip) {
            gld16(gB + k0, &Bs[b][tid * 8]);
            gld16(gB + half + k0, &Bs[b][2048 + tid * 8]);
        }
    };

    stage(0, 0);
    int cur = 0;
    const int l15 = lane & 15;
    const int kq = ((lane >> 4) ^ ((l15 >> 1) & 3)) * 8;
    for (int k0 = 0; k0 < K2; k0 += 32) {
        const bool lo = (k0 < H);
        __syncthreads();
        if (k0 + 32 < K2) stage(cur ^ 1, k0 + 32);
        bf16x8 af[4], bfr[4];
#pragma unroll
        for (int i = 0; i < 4; ++i)
            af[i] = *(const bf16x8*)&As[cur][(wr * 64 + i * 16 + l15) * 32 + kq];
#pragma unroll
        for (int j = 0; j < 4; ++j) {
            if ((j == 2 && !lo) || (j == 3 && lo)) continue;
            bfr[j] = *(const bf16x8*)&Bs[cur][(wc * 64 + j * 16 + l15) * 32 + kq];
        }
#pragma unroll
        for (int i = 0; i < 4; ++i)
#pragma unroll
            for (int j = 0; j < 4; ++j) {
                if ((j == 2 && !lo) || (j == 3 && lo)) continue;
                acc[i][j] = __builtin_amdgcn_mfma_f32_16x16x32_bf16(af[i], bfr[j], acc[i][j], 0, 0, 0);
            }
        cur ^= 1;
    }

    // gating epilogue: frag j = chunk j (0=r, 1=z, 2=inn, 3=hn)
    const int cr = (lane >> 4) * 4;
    const int c = cs * 32 + wc * 16 + (lane & 15);  // real col
    const float bsr = bih[c] + bhh[c];
    const float bsz = bih[H + c] + bhh[H + c];
    const float bin = bih[2 * H + c];
    const float bhn = bhh[2 * H + c];
#pragma unroll
    for (int i = 0; i < 4; ++i) {
#pragma unroll
        for (int r = 0; r < 4; ++r) {
            const long row = row0 + wr * 64 + i * 16 + cr + r;
            if (row >= M) continue;
            float rg = sigmoidf(acc[i][0][r] + bsr);
            float zg = sigmoidf(acc[i][1][r] + bsz);
            float ng = tanhf(acc[i][2][r] + bin + rg * (acc[i][3][r] + bhn));
            float o = (1.f - zg) * ng + zg * prevf[row * (long)H + c];
            outF[row * (long)H + c] = o;
            if (WRITEB) outB[row * (long)H + c] = f2b(o);
        }
    }
}

// ---------------------------------------------------------------------------
// CSR build: count -> scan(+dinv) -> fill
// ---------------------------------------------------------------------------
__global__ void cnt_kernel(const int* __restrict__ cols, int* __restrict__ cnt, int E) {
    int e = blockIdx.x * 256 + threadIdx.x;
    if (e < E) atomicAdd(&cnt[cols[e]], 1);
}

__global__ void scan1(const int* __restrict__ cnt, int* __restrict__ off,
                      int* __restrict__ bsum, float* __restrict__ dinv, int n) {
    __shared__ int sm[256];
    int i = blockIdx.x * 256 + threadIdx.x;
    int v = (i < n) ? cnt[i] : 0;
    if (i < n) dinv[i] = rsqrtf((float)v + 1.0f);   // +1 self-loop
    sm[threadIdx.x] = v;
    __syncthreads();
    for (int s = 1; s < 256; s <<= 1) {
        int t = (threadIdx.x >= s) ? sm[threadIdx.x - s] : 0;
        __syncthreads();
        sm[threadIdx.x] += t;
        __syncthreads();
    }
    if (i < n) off[i + 1] = sm[threadIdx.x];
    if (threadIdx.x == 255) bsum[blockIdx.x] = sm[255];
}

__global__ void scan2(int* __restrict__ bsum, int nb) {
    __shared__ int sm[256];
    int v = (threadIdx.x < nb) ? bsum[threadIdx.x] : 0;
    sm[threadIdx.x] = v;
    __syncthreads();
    for (int s = 1; s < 256; s <<= 1) {
        int t = (threadIdx.x >= s) ? sm[threadIdx.x - s] : 0;
        __syncthreads();
        sm[threadIdx.x] += t;
        __syncthreads();
    }
    if (threadIdx.x < nb) bsum[threadIdx.x] = sm[threadIdx.x] - v;  // exclusive
}

__global__ void scan3(int* __restrict__ off, const int* __restrict__ bsum, int n) {
    int i = blockIdx.x * 256 + threadIdx.x;
    if (i < n) off[i + 1] += bsum[blockIdx.x];
    if (i == 0) off[0] = 0;
}

__global__ void fill_csr(const int* __restrict__ rows, const int* __restrict__ cols,
                         const float* __restrict__ dinv, const int* __restrict__ off,
                         int* __restrict__ cursor, int* __restrict__ srow,
                         float* __restrict__ snorm, int E) {
    int e = blockIdx.x * 256 + threadIdx.x;
    if (e >= E) return;
    int r = rows[e], c = cols[e];
    int p = off[c] + atomicAdd(&cursor[c], 1);
    srow[p] = r;
    snorm[p] = dinv[r] * dinv[c];
}

// ---------------------------------------------------------------------------
// Gather-aggregate over H=128 feats, one wave per dest node, 4x unrolled.
// Output row stride OS; EPI adds bias+lrelu.
// ---------------------------------------------------------------------------
template <int OS, bool EPI>
__global__ __launch_bounds__(256)
void gather_agg(const short* __restrict__ hwb, const int* __restrict__ off,
                const int* __restrict__ srow, const float* __restrict__ snorm,
                const float* __restrict__ dinv, const float* __restrict__ bias,
                short* __restrict__ aggb, int n) {
    constexpr int H = 128;
    int t = blockIdx.x * 256 + threadIdx.x;
    int c = t >> 6, l = t & 63;
    if (c >= n) return;
    const int fo = l * 2;
    float acc0, acc1;
    {
        float dd = dinv[c] * dinv[c];
        s16x2 v = *(const s16x2*)&hwb[(long)c * H + fo];
        acc0 = b2f(v[0]) * dd;
        acc1 = b2f(v[1]) * dd;
    }
    int e = off[c];
    const int e1 = off[c + 1];
    for (; e + 3 < e1; e += 4) {
        int r0 = srow[e], r1 = srow[e + 1], r2 = srow[e + 2], r3 = srow[e + 3];
        float n0 = snorm[e], n1 = snorm[e + 1], n2 = snorm[e + 2], n3 = snorm[e + 3];
        s16x2 v0 = *(const s16x2*)&hwb[(long)r0 * H + fo];
        s16x2 v1 = *(const s16x2*)&hwb[(long)r1 * H + fo];
        s16x2 v2 = *(const s16x2*)&hwb[(long)r2 * H + fo];
        s16x2 v3 = *(const s16x2*)&hwb[(long)r3 * H + fo];
        acc0 += b2f(v0[0]) * n0 + b2f(v1[0]) * n1 + b2f(v2[0]) * n2 + b2f(v3[0]) * n3;
        acc1 += b2f(v0[1]) * n0 + b2f(v1[1]) * n1 + b2f(v2[1]) * n2 + b2f(v3[1]) * n3;
    }
    for (; e < e1; ++e) {
        int r0 = srow[e];
        float n0 = snorm[e];
        s16x2 v0 = *(const s16x2*)&hwb[(long)r0 * H + fo];
        acc0 += b2f(v0[0]) * n0;
        acc1 += b2f(v0[1]) * n0;
    }
    s16x2 o;
    if (EPI) {
        o[0] = f2b(lrelu(acc0 + bias[fo]));
        o[1] = f2b(lrelu(acc1 + bias[fo + 1]));
    } else {
        o[0] = f2b(acc0);
        o[1] = f2b(acc1);
    }
    *(s16x2*)&aggb[(long)c * OS + fo] = o;
}

// ---------------------------------------------------------------------------
// Edge scores from bf16 emb2: one 64-lane wave per query edge
// ---------------------------------------------------------------------------
__global__ void edge_score_b(const short* __restrict__ emb2b, const int* __restrict__ eli,
                             const float* __restrict__ ea, const float* __restrict__ pw,
                             const float* __restrict__ pb, float* __restrict__ scores, int Q) {
    int t = blockIdx.x * 256 + threadIdx.x;
    int e = t >> 6, l = t & 63;
    if (e >= Q) return;
    int s = eli[e], d = eli[Q + e];
    const int f = l * 2;
    s16x2 vs = *(const s16x2*)&emb2b[(long)s * 128 + f];
    s16x2 vd = *(const s16x2*)&emb2b[(long)d * 128 + f];
    float acc = b2f(vs[0]) * pw[f] + b2f(vs[1]) * pw[f + 1]
              + b2f(vd[0]) * pw[128 + f] + b2f(vd[1]) * pw[128 + f + 1];
    if (l < 16) acc += ea[(long)e * 16 + l] * pw[256 + l];
#pragma unroll
    for (int off = 32; off > 0; off >>= 1) acc += __shfl_down(acc, off);
    if (l == 0) scores[e] = acc + pb[0];
}

// ---------------------------------------------------------------------------

extern "C" void kernel_launch(void* const* d_in, const int* in_sizes, int n_in,
                              void* d_out, int out_size, void* d_ws, size_t ws_size,
                              hipStream_t stream) {
    const float* x       = (const float*)d_in[0];
    const int*   ei      = (const int*)d_in[1];
    const int*   eli     = (const int*)d_in[2];
    const float* eattr   = (const float*)d_in[3];
    const float* prev1   = (const float*)d_in[4];
    const float* prev2   = (const float*)d_in[5];
    const float* pre1_W  = (const float*)d_in[6];
    const float* pre1_b  = (const float*)d_in[7];
    const float* pre2_W  = (const float*)d_in[8];
    const float* pre2_b  = (const float*)d_in[9];
    const float* conv1_W = (const float*)d_in[10];
    const float* conv1_b = (const float*)d_in[11];
    const float* conv2_W = (const float*)d_in[12];
    const float* conv2_b = (const float*)d_in[13];
    const float* g1_Wih  = (const float*)d_in[14];
    const float* g1_Whh  = (const float*)d_in[15];
    const float* g1_bih  = (const float*)d_in[16];
    const float* g1_bhh  = (const float*)d_in[17];
    const float* g2_Wih  = (const float*)d_in[18];
    const float* g2_Whh  = (const float*)d_in[19];
    const float* g2_bih  = (const float*)d_in[20];
    const float* g2_bhh  = (const float*)d_in[21];
    const float* post_W  = (const float*)d_in[22];
    const float* post_b  = (const float*)d_in[23];

    float* out    = (float*)d_out;
    float* scores = out;                      // [NQ]
    float* emb1   = out + NQ;                 // [N,256]
    float* emb2   = emb1 + (long)NN * 256;    // [N,128]

    // workspace layout (bytes)
    char* ws = (char*)d_ws;
    const long S256 = MP * 256 * 2;           // 25,624,576
    const long S128 = MP * 128 * 2;           // 12,812,288
    short* R1  = (short*)ws;                          // xb -> G1 -> AP2
    short* R2  = (short*)(ws + S256);                 // h1b -> emb1b
    short* R3  = (short*)(ws + 2 * S256);             // h2b -> hw2b -> emb2b
    short* AP1 = (short*)(ws + 2 * S256 + S128);      // [MP][512]
    short* AP2 = R1;                                  // [MP][256], aliases R1
    char*  wts = ws + 4 * S256 + S128;
    short* pre1T  = (short*)wts;            // [256][256]
    short* pre2T  = pre1T + 256 * 256;      // [128][256]
    short* conv1T = pre2T + 128 * 256;      // [256][128]
    short* conv2T = conv1T + 256 * 128;     // [128][256]
    short* W1g1   = conv2T + 128 * 256;     // [1024][512]
    short* W1g2   = W1g1 + 1024 * 512;      // [512][256]
    float* dinv   = (float*)(W1g2 + 512 * 256);   // [NN]
    int*   cnt    = (int*)(dinv + NN);            // [NN]   (cnt+cursor adjacent
    int*   cursor = cnt + NN;                     // [NN]    -> single memset)
    int*   off    = cursor + NN;                  // [NN+1]
    int*   bsum   = off + NN + 1;                 // [256]
    int*   srow   = bsum + 256;                   // [NE]
    float* snorm  = (float*)(srow + NE);          // [NE]

    const int* rows = ei;
    const int* cols = ei + NE;

    dim3 blk(256);
    const int NB = (NN + 255) / 256;   // 196

    // --- single prep kernel: xb, prev1->AP1, all weight transforms ---
    const long PREP = MP * 256 + (long)NN * 256 + 65536 + 3 * 32768 + 524288 + 131072;
    prep_all<<<(int)((PREP + 255) / 256), blk, 0, stream>>>(
        x, prev1, pre1_W, pre2_W, conv1_W, conv2_W,
        g1_Wih, g1_Whh, g2_Wih, g2_Whh,
        R1, AP1, pre1T, pre2T, conv1T, conv2T, W1g1, W1g2);

    // --- CSR build (once, reused by both layers) ---
    hipMemsetAsync(cnt, 0, 2 * NN * sizeof(int), stream);   // cnt + cursor
    cnt_kernel<<<(NE + 255) / 256, blk, 0, stream>>>(cols, cnt, NE);
    scan1<<<NB, blk, 0, stream>>>(cnt, off, bsum, dinv, NN);
    scan2<<<1, blk, 0, stream>>>(bsum, NB);
    scan3<<<NB, blk, 0, stream>>>(off, bsum, NN);
    fill_csr<<<(NE + 255) / 256, blk, 0, stream>>>(rows, cols, dinv, off, cursor, srow, snorm, NE);

    // --- dense pre-layers ---
    gemm_mfma<1><<<782, blk, 0, stream>>>(R1, pre1T, pre1_b, R2, 256, 256, 2, 782);
    gemm_mfma<1><<<391, blk, 0, stream>>>(R2, pre2T, pre2_b, R3, 256, 128, 1, 391);

    // --- GCN1: aggregate on 128-dim h2 (raw), then conv1 GEMM -> AP1 left ---
    gather_agg<128, false><<<(NN + 3) / 4, blk, 0, stream>>>(R3, off, srow, snorm, dinv, nullptr, R1, NN);
    gemm_mfma<1><<<782, blk, 0, stream>>>(R1, conv1T, conv1_b, AP1, 128, 512, 2, 782);

    // --- GRU1 (wide fused, K-split, XCD swizzle) -> emb1 fp32 + emb1b (R2) ---
    gru_wide<256, true><<<3128, blk, 0, stream>>>(AP1, W1g1, prev1, g1_bih, g1_bhh,
                                                  emb1, R2, NN, 8, 3128);

    // --- prev2 -> AP2 right half (R1's G1 role ended at conv1) ---
    f2b_strided<<<(int)(((long)NN * 128 + 255) / 256), blk, 0, stream>>>(prev2, AP2, 128, (long)NN * 128);

    // --- conv2 ---
    gemm_mfma<0><<<391, blk, 0, stream>>>(R2, conv2T, nullptr, R3, 256, 128, 1, 391);

    // --- GCN2: aggregate (fused bias+lrelu) -> AP2 left half ---
    gather_agg<256, true><<<(NN + 3) / 4, blk, 0, stream>>>(R3, off, srow, snorm, dinv, conv2_b, AP2, NN);

    // --- GRU2 (wide fused, K-split, XCD swizzle) -> emb2 fp32 + emb2b (R3) ---
    gru_wide<128, true><<<1564, blk, 0, stream>>>(AP2, W1g2, prev2, g2_bih, g2_bhh,
                                                  emb2, R3, NN, 4, 1564);

    // --- edge scores (bf16 gather) ---
    edge_score_b<<<NQ / 4, blk, 0, stream>>>(R3, eli, eattr, post_W, post_b, scores, NQ);
}

// Round 8
// 459.348 us; speedup vs baseline: 1.2894x; 1.0469x over previous
//
#include <hip/hip_runtime.h>
#include <hip/hip_bf16.h>

#define DEVFN __device__ __forceinline__

constexpr int NN = 50000;
constexpr int NE = 800000;
constexpr int NQ = 200000;
constexpr long MP = 50048;   // NN padded to multiple of 128

typedef __attribute__((ext_vector_type(8))) short bf16x8;
typedef __attribute__((ext_vector_type(2))) short s16x2;
typedef __attribute__((ext_vector_type(2))) float f32x2;
typedef __attribute__((ext_vector_type(4))) float f32x4;
typedef __attribute__((address_space(1))) const void gv_t;
typedef __attribute__((address_space(3))) void lv_t;

DEVFN float lrelu(float x) { return x > 0.f ? x : 0.01f * x; }
DEVFN float sigmoidf(float x) { return 1.f / (1.f + __expf(-x)); }
DEVFN float tanh_fast(float x) {
    // exact enough for bf16 output; 1 exp + 1 div, clamped so exp stays finite
    float xc = fminf(fmaxf(x, -15.f), 15.f);
    float t = __expf(2.f * xc);
    return (t - 1.f) / (t + 1.f);
}

DEVFN short f2b(float v) {
    __hip_bfloat16 h = __float2bfloat16(v);
    return *reinterpret_cast<short*>(&h);
}
DEVFN float b2f(short s) {
    union { unsigned u; float f; } z;
    z.u = ((unsigned)(unsigned short)s) << 16;
    return z.f;
}
DEVFN void gld16(const void* g, void* l) {
    __builtin_amdgcn_global_load_lds((gv_t*)g, (lv_t*)l, 16, 0, 0);
}

#define WAITV4 asm volatile("s_waitcnt vmcnt(4)" ::: "memory")
#define WAITV0 asm volatile("s_waitcnt vmcnt(0)" ::: "memory")
#define CFENCE asm volatile("" ::: "memory")

// ---------------------------------------------------------------------------
// Bijective XCD-chunked swizzle (m204): each XCD gets a contiguous work range,
// ordered col-strip-fastest -> A-panel row band stays in that XCD's L2.
// ---------------------------------------------------------------------------
DEVFN void swz_rc(int d, int nwg, int NC, int& rw, int& cs) {
    int q0 = nwg >> 3, rr = nwg & 7;
    int xcd = d & 7, idx = d >> 3;
    int w = (xcd < rr ? xcd * (q0 + 1) : rr * (q0 + 1) + (xcd - rr) * q0) + idx;
    rw = w / NC;
    cs = w - rw * NC;
}

// ---------------------------------------------------------------------------
// GRU interleaved-weight value: W1 [4H][2H]; row n' = g16*64 + chunk*16 + cl;
// real col c = g16*16+cl; chunks: r, z, inn (k<H only), hn (k>=H only).
// ---------------------------------------------------------------------------
template <int H>
DEVFN float gruw_val(const float* Wih, const float* Whh, int i) {
    constexpr int K2 = 2 * H, W3 = 3 * H;
    int np = i / K2, k = i % K2;
    int g16 = np >> 6, chunk = (np >> 4) & 3, cl = np & 15;
    int c = g16 * 16 + cl;
    if (chunk == 0) return (k < H) ? Wih[(long)k * W3 + c] : Whh[(long)(k - H) * W3 + c];
    if (chunk == 1) return (k < H) ? Wih[(long)k * W3 + H + c] : Whh[(long)(k - H) * W3 + H + c];
    if (chunk == 2) return (k < H) ? Wih[(long)k * W3 + 2 * H + c] : 0.f;
    return (k < H) ? 0.f : Whh[(long)(k - H) * W3 + 2 * H + c];
}

// ---------------------------------------------------------------------------
// One mega prep kernel: xb, prev1->AP1 right half, 4 transposed weights,
// 2 interleaved GRU weights. Flat range dispatch.
// ---------------------------------------------------------------------------
__global__ void prep_all(const float* __restrict__ x, const float* __restrict__ prev1,
                         const float* __restrict__ pre1W, const float* __restrict__ pre2W,
                         const float* __restrict__ conv1W, const float* __restrict__ conv2W,
                         const float* __restrict__ g1ih, const float* __restrict__ g1hh,
                         const float* __restrict__ g2ih, const float* __restrict__ g2hh,
                         short* __restrict__ xb, short* __restrict__ AP1,
                         short* __restrict__ pre1T, short* __restrict__ pre2T,
                         short* __restrict__ conv1T, short* __restrict__ conv2T,
                         short* __restrict__ W1g1, short* __restrict__ W1g2) {
    long i = (long)blockIdx.x * 256 + threadIdx.x;
    if (i < MP * 256) {                                   // xb (zero-padded)
        xb[i] = (i < (long)NN * 256) ? f2b(x[i]) : (short)0;
        return;
    }
    i -= MP * 256;
    if (i < (long)NN * 256) {                             // prev1 -> AP1 right half
        long r = i >> 8; int c = (int)(i & 255);
        AP1[r * 512 + 256 + c] = f2b(prev1[i]);
        return;
    }
    i -= (long)NN * 256;
    if (i < 65536) { int ii = (int)i, n = ii >> 8, k = ii & 255; pre1T[ii] = f2b(pre1W[k * 256 + n]); return; }
    i -= 65536;
    if (i < 32768) { int ii = (int)i, n = ii >> 8, k = ii & 255; pre2T[ii] = f2b(pre2W[k * 128 + n]); return; }
    i -= 32768;
    if (i < 32768) { int ii = (int)i, n = ii >> 7, k = ii & 127; conv1T[ii] = f2b(conv1W[k * 256 + n]); return; }
    i -= 32768;
    if (i < 32768) { int ii = (int)i, n = ii >> 8, k = ii & 255; conv2T[ii] = f2b(conv2W[k * 128 + n]); return; }
    i -= 32768;
    if (i < 524288) { W1g1[i] = f2b(gruw_val<256>(g1ih, g1hh, (int)i)); return; }
    i -= 524288;
    if (i < 131072) W1g2[i] = f2b(gruw_val<128>(g2ih, g2hh, (int)i));
}

// ---------------------------------------------------------------------------
// bf16 MFMA GEMM, 3-buffer counted-vmcnt pipeline + XOR slot swizzle + XCD
// block swizzle. C = epi(A[Mpad][K] @ Bt[Nt][K]^T + bias); BM=BN=128, 4 waves.
// ---------------------------------------------------------------------------
template <int EPI, int K>
__global__ __launch_bounds__(256)
void gemm_mfma(const short* __restrict__ A, const short* __restrict__ Bt,
               const float* __restrict__ bias,
               short* __restrict__ Cb, int obS, int NC, int nwg) {
    constexpr int NS = K / 32;
    __shared__ alignas(16) short As[3][4096];
    __shared__ alignas(16) short Bs[3][4096];
    const int tid = threadIdx.x;
    const int lane = tid & 63, w = tid >> 6;
    const int wr = w >> 1, wc = w & 1;
    int rw, cs;
    swz_rc(blockIdx.x, nwg, NC, rw, cs);
    const long row0 = (long)rw * 128;
    const long col0 = (long)cs * 128;

    f32x4 acc[4][4] = {};

    const int kcs = ((tid & 3) ^ ((tid >> 3) & 3)) * 8;  // pre-swizzled global slot
    const short* gA = A + (row0 + (tid >> 2)) * (long)K + kcs;
    const short* gB = Bt + (col0 + (tid >> 2)) * (long)K + kcs;
    const long half = 64 * (long)K;

    auto stage = [&](int b, int k0) {
        gld16(gA + k0, &As[b][tid * 8]);
        gld16(gA + half + k0, &As[b][2048 + tid * 8]);
        gld16(gB + k0, &Bs[b][tid * 8]);
        gld16(gB + half + k0, &Bs[b][2048 + tid * 8]);
    };

    stage(0, 0);
    stage(1, 32);
    const int l15 = lane & 15;
    const int kq = ((lane >> 4) ^ ((l15 >> 1) & 3)) * 8;  // swizzled slot on read
#pragma unroll
    for (int t = 0; t < NS; ++t) {
        if (t + 1 < NS) { WAITV4; } else { WAITV0; }
        __builtin_amdgcn_s_barrier();
        CFENCE;
        if (t + 2 < NS) stage((t + 2) % 3, (t + 2) * 32);
        const int cur = t % 3;
        bf16x8 af[4], bfr[4];
#pragma unroll
        for (int i = 0; i < 4; ++i)
            af[i] = *(const bf16x8*)&As[cur][(wr * 64 + i * 16 + l15) * 32 + kq];
#pragma unroll
        for (int j = 0; j < 4; ++j)
            bfr[j] = *(const bf16x8*)&Bs[cur][(wc * 64 + j * 16 + l15) * 32 + kq];
#pragma unroll
        for (int i = 0; i < 4; ++i)
#pragma unroll
            for (int j = 0; j < 4; ++j)
                acc[i][j] = __builtin_amdgcn_mfma_f32_16x16x32_bf16(af[i], bfr[j], acc[i][j], 0, 0, 0);
    }

    const int cr = (lane >> 4) * 4, cc = lane & 15;
#pragma unroll
    for (int i = 0; i < 4; ++i) {
#pragma unroll
        for (int j = 0; j < 4; ++j) {
            const long col = col0 + wc * 64 + j * 16 + cc;
            float bv = (EPI == 1) ? bias[col] : 0.f;
#pragma unroll
            for (int r = 0; r < 4; ++r) {
                const long row = row0 + wr * 64 + i * 16 + cr + r;
                float v = acc[i][j][r];
                if (EPI == 1) v = lrelu(v + bv);
                Cb[row * obS + col] = f2b(v);
            }
        }
    }
}

// ---------------------------------------------------------------------------
// Wide fused GRU, 3-buffer counted-vmcnt pipeline, 128x128 tile, 4 waves,
// K-split on MFMA/ds_read (chunk 2 only k<H, chunk 3 only k>=H; staging
// uniform for constant vmcnt), XCD block swizzle.
// ---------------------------------------------------------------------------
template <int H, bool WRITEB>
__global__ __launch_bounds__(256)
void gru_wide(const short* __restrict__ AP, const short* __restrict__ W1,
              const float* __restrict__ prevf,
              const float* __restrict__ bih, const float* __restrict__ bhh,
              float* __restrict__ outF, short* __restrict__ outB, int M,
              int NC, int nwg) {
    constexpr int K2 = 2 * H;
    constexpr int NS = K2 / 32;
    __shared__ alignas(16) short As[3][4096];
    __shared__ alignas(16) short Bs[3][4096];
    const int tid = threadIdx.x;
    const int lane = tid & 63, w = tid >> 6;
    const int wr = w >> 1, wc = w & 1;
    int rw, cs;
    swz_rc(blockIdx.x, nwg, NC, rw, cs);
    const long row0 = (long)rw * 128;

    f32x4 acc[4][4] = {};

    const int kcs = ((tid & 3) ^ ((tid >> 3) & 3)) * 8;
    const short* gA = AP + (row0 + (tid >> 2)) * (long)K2 + kcs;
    const short* gB = W1 + ((long)cs * 128 + (tid >> 2)) * (long)K2 + kcs;
    const long half = 64 * (long)K2;

    auto stage = [&](int b, int k0) {
        gld16(gA + k0, &As[b][tid * 8]);
        gld16(gA + half + k0, &As[b][2048 + tid * 8]);
        gld16(gB + k0, &Bs[b][tid * 8]);
        gld16(gB + half + k0, &Bs[b][2048 + tid * 8]);
    };

    stage(0, 0);
    stage(1, 32);
    const int l15 = lane & 15;
    const int kq = ((lane >> 4) ^ ((l15 >> 1) & 3)) * 8;
#pragma unroll
    for (int t = 0; t < NS; ++t) {
        const bool lo = (t * 32 < H);
        if (t + 1 < NS) { WAITV4; } else { WAITV0; }
        __builtin_amdgcn_s_barrier();
        CFENCE;
        if (t + 2 < NS) stage((t + 2) % 3, (t + 2) * 32);
        const int cur = t % 3;
        bf16x8 af[4], bfr[4];
#pragma unroll
        for (int i = 0; i < 4; ++i)
            af[i] = *(const bf16x8*)&As[cur][(wr * 64 + i * 16 + l15) * 32 + kq];
#pragma unroll
        for (int j = 0; j < 4; ++j) {
            if ((j == 2 && !lo) || (j == 3 && lo)) continue;
            bfr[j] = *(const bf16x8*)&Bs[cur][(wc * 64 + j * 16 + l15) * 32 + kq];
        }
#pragma unroll
        for (int i = 0; i < 4; ++i)
#pragma unroll
            for (int j = 0; j < 4; ++j) {
                if ((j == 2 && !lo) || (j == 3 && lo)) continue;
                acc[i][j] = __builtin_amdgcn_mfma_f32_16x16x32_bf16(af[i], bfr[j], acc[i][j], 0, 0, 0);
            }
    }

    // gating epilogue: frag j = chunk j (0=r, 1=z, 2=inn, 3=hn)
    const int cr = (lane >> 4) * 4;
    const int c = cs * 32 + wc * 16 + (lane & 15);  // real col
    const float bsr = bih[c] + bhh[c];
    const float bsz = bih[H + c] + bhh[H + c];
    const float bin = bih[2 * H + c];
    const float bhn = bhh[2 * H + c];
#pragma unroll
    for (int i = 0; i < 4; ++i) {
#pragma unroll
        for (int r = 0; r < 4; ++r) {
            const long row = row0 + wr * 64 + i * 16 + cr + r;
            if (row >= M) continue;
            float rg = sigmoidf(acc[i][0][r] + bsr);
            float zg = sigmoidf(acc[i][1][r] + bsz);
            float ng = tanh_fast(acc[i][2][r] + bin + rg * (acc[i][3][r] + bhn));
            float o = (1.f - zg) * ng + zg * prevf[row * (long)H + c];
            outF[row * (long)H + c] = o;
            if (WRITEB) outB[row * (long)H + c] = f2b(o);
        }
    }
}

// ---------------------------------------------------------------------------
// CSR build: count -> scan(+dinv) -> fill
// ---------------------------------------------------------------------------
__global__ void cnt_kernel(const int* __restrict__ cols, int* __restrict__ cnt, int E) {
    int e = blockIdx.x * 256 + threadIdx.x;
    if (e < E) atomicAdd(&cnt[cols[e]], 1);
}

__global__ void scan1(const int* __restrict__ cnt, int* __restrict__ off,
                      int* __restrict__ bsum, float* __restrict__ dinv, int n) {
    __shared__ int sm[256];
    int i = blockIdx.x * 256 + threadIdx.x;
    int v = (i < n) ? cnt[i] : 0;
    if (i < n) dinv[i] = rsqrtf((float)v + 1.0f);   // +1 self-loop
    sm[threadIdx.x] = v;
    __syncthreads();
    for (int s = 1; s < 256; s <<= 1) {
        int t = (threadIdx.x >= s) ? sm[threadIdx.x - s] : 0;
        __syncthreads();
        sm[threadIdx.x] += t;
        __syncthreads();
    }
    if (i < n) off[i + 1] = sm[threadIdx.x];
    if (threadIdx.x == 255) bsum[blockIdx.x] = sm[255];
}

__global__ void scan2(int* __restrict__ bsum, int nb) {
    __shared__ int sm[256];
    int v = (threadIdx.x < nb) ? bsum[threadIdx.x] : 0;
    sm[threadIdx.x] = v;
    __syncthreads();
    for (int s = 1; s < 256; s <<= 1) {
        int t = (threadIdx.x >= s) ? sm[threadIdx.x - s] : 0;
        __syncthreads();
        sm[threadIdx.x] += t;
        __syncthreads();
    }
    if (threadIdx.x < nb) bsum[threadIdx.x] = sm[threadIdx.x] - v;  // exclusive
}

__global__ void scan3(int* __restrict__ off, const int* __restrict__ bsum, int n) {
    int i = blockIdx.x * 256 + threadIdx.x;
    if (i < n) off[i + 1] += bsum[blockIdx.x];
    if (i == 0) off[0] = 0;
}

__global__ void fill_csr(const int* __restrict__ rows, const int* __restrict__ cols,
                         const float* __restrict__ dinv, const int* __restrict__ off,
                         int* __restrict__ cursor, int* __restrict__ srow,
                         float* __restrict__ snorm, int E) {
    int e = blockIdx.x * 256 + threadIdx.x;
    if (e >= E) return;
    int r = rows[e], c = cols[e];
    int p = off[c] + atomicAdd(&cursor[c], 1);
    srow[p] = r;
    snorm[p] = dinv[r] * dinv[c];
}

// ---------------------------------------------------------------------------
// Gather-aggregate over H=128 feats, one wave per dest node, 4x unrolled.
// Output row stride OS; EPI adds bias+lrelu; PREV also copies prevf row into
// the right half (cols [128,256) of OS=256) as bf16.
// ---------------------------------------------------------------------------
template <int OS, bool EPI, bool PREV>
__global__ __launch_bounds__(256)
void gather_agg(const short* __restrict__ hwb, const int* __restrict__ off,
                const int* __restrict__ srow, const float* __restrict__ snorm,
                const float* __restrict__ dinv, const float* __restrict__ bias,
                const float* __restrict__ prevf,
                short* __restrict__ aggb, int n) {
    constexpr int H = 128;
    int t = blockIdx.x * 256 + threadIdx.x;
    int c = t >> 6, l = t & 63;
    if (c >= n) return;
    const int fo = l * 2;
    float acc0, acc1;
    {
        float dd = dinv[c] * dinv[c];
        s16x2 v = *(const s16x2*)&hwb[(long)c * H + fo];
        acc0 = b2f(v[0]) * dd;
        acc1 = b2f(v[1]) * dd;
    }
    int e = off[c];
    const int e1 = off[c + 1];
    for (; e + 3 < e1; e += 4) {
        int r0 = srow[e], r1 = srow[e + 1], r2 = srow[e + 2], r3 = srow[e + 3];
        float n0 = snorm[e], n1 = snorm[e + 1], n2 = snorm[e + 2], n3 = snorm[e + 3];
        s16x2 v0 = *(const s16x2*)&hwb[(long)r0 * H + fo];
        s16x2 v1 = *(const s16x2*)&hwb[(long)r1 * H + fo];
        s16x2 v2 = *(const s16x2*)&hwb[(long)r2 * H + fo];
        s16x2 v3 = *(const s16x2*)&hwb[(long)r3 * H + fo];
        acc0 += b2f(v0[0]) * n0 + b2f(v1[0]) * n1 + b2f(v2[0]) * n2 + b2f(v3[0]) * n3;
        acc1 += b2f(v0[1]) * n0 + b2f(v1[1]) * n1 + b2f(v2[1]) * n2 + b2f(v3[1]) * n3;
    }
    for (; e < e1; ++e) {
        int r0 = srow[e];
        float n0 = snorm[e];
        s16x2 v0 = *(const s16x2*)&hwb[(long)r0 * H + fo];
        acc0 += b2f(v0[0]) * n0;
        acc1 += b2f(v0[1]) * n0;
    }
    s16x2 o;
    if (EPI) {
        o[0] = f2b(lrelu(acc0 + bias[fo]));
        o[1] = f2b(lrelu(acc1 + bias[fo + 1]));
    } else {
        o[0] = f2b(acc0);
        o[1] = f2b(acc1);
    }
    *(s16x2*)&aggb[(long)c * OS + fo] = o;
    if (PREV) {
        f32x2 p = *(const f32x2*)&prevf[(long)c * H + fo];
        s16x2 pb;
        pb[0] = f2b(p[0]);
        pb[1] = f2b(p[1]);
        *(s16x2*)&aggb[(long)c * OS + H + fo] = pb;
    }
}

// ---------------------------------------------------------------------------
// Edge scores from bf16 emb2: one 64-lane wave per query edge
// ---------------------------------------------------------------------------
__global__ void edge_score_b(const short* __restrict__ emb2b, const int* __restrict__ eli,
                             const float* __restrict__ ea, const float* __restrict__ pw,
                             const float* __restrict__ pb, float* __restrict__ scores, int Q) {
    int t = blockIdx.x * 256 + threadIdx.x;
    int e = t >> 6, l = t & 63;
    if (e >= Q) return;
    int s = eli[e], d = eli[Q + e];
    const int f = l * 2;
    s16x2 vs = *(const s16x2*)&emb2b[(long)s * 128 + f];
    s16x2 vd = *(const s16x2*)&emb2b[(long)d * 128 + f];
    float acc = b2f(vs[0]) * pw[f] + b2f(vs[1]) * pw[f + 1]
              + b2f(vd[0]) * pw[128 + f] + b2f(vd[1]) * pw[128 + f + 1];
    if (l < 16) acc += ea[(long)e * 16 + l] * pw[256 + l];
#pragma unroll
    for (int off = 32; off > 0; off >>= 1) acc += __shfl_down(acc, off);
    if (l == 0) scores[e] = acc + pb[0];
}

// ---------------------------------------------------------------------------

extern "C" void kernel_launch(void* const* d_in, const int* in_sizes, int n_in,
                              void* d_out, int out_size, void* d_ws, size_t ws_size,
                              hipStream_t stream) {
    const float* x       = (const float*)d_in[0];
    const int*   ei      = (const int*)d_in[1];
    const int*   eli     = (const int*)d_in[2];
    const float* eattr   = (const float*)d_in[3];
    const float* prev1   = (const float*)d_in[4];
    const float* prev2   = (const float*)d_in[5];
    const float* pre1_W  = (const float*)d_in[6];
    const float* pre1_b  = (const float*)d_in[7];
    const float* pre2_W  = (const float*)d_in[8];
    const float* pre2_b  = (const float*)d_in[9];
    const float* conv1_W = (const float*)d_in[10];
    const float* conv1_b = (const float*)d_in[11];
    const float* conv2_W = (const float*)d_in[12];
    const float* conv2_b = (const float*)d_in[13];
    const float* g1_Wih  = (const float*)d_in[14];
    const float* g1_Whh  = (const float*)d_in[15];
    const float* g1_bih  = (const float*)d_in[16];
    const float* g1_bhh  = (const float*)d_in[17];
    const float* g2_Wih  = (const float*)d_in[18];
    const float* g2_Whh  = (const float*)d_in[19];
    const float* g2_bih  = (const float*)d_in[20];
    const float* g2_bhh  = (const float*)d_in[21];
    const float* post_W  = (const float*)d_in[22];
    const float* post_b  = (const float*)d_in[23];

    float* out    = (float*)d_out;
    float* scores = out;                      // [NQ]
    float* emb1   = out + NQ;                 // [N,256]
    float* emb2   = emb1 + (long)NN * 256;    // [N,128]

    // workspace layout (bytes)
    char* ws = (char*)d_ws;
    const long S256 = MP * 256 * 2;           // 25,624,576
    const long S128 = MP * 128 * 2;           // 12,812,288
    short* R1  = (short*)ws;                          // xb -> G1 -> AP2
    short* R2  = (short*)(ws + S256);                 // h1b -> emb1b
    short* R3  = (short*)(ws + 2 * S256);             // h2b -> hw2b -> emb2b
    short* AP1 = (short*)(ws + 2 * S256 + S128);      // [MP][512]
    short* AP2 = R1;                                  // [MP][256], aliases R1
    char*  wts = ws + 4 * S256 + S128;
    short* pre1T  = (short*)wts;            // [256][256]
    short* pre2T  = pre1T + 256 * 256;      // [128][256]
    short* conv1T = pre2T + 128 * 256;      // [256][128]
    short* conv2T = conv1T + 256 * 128;     // [128][256]
    short* W1g1   = conv2T + 128 * 256;     // [1024][512]
    short* W1g2   = W1g1 + 1024 * 512;      // [512][256]
    float* dinv   = (float*)(W1g2 + 512 * 256);   // [NN]
    int*   cnt    = (int*)(dinv + NN);            // [NN]   (cnt+cursor adjacent
    int*   cursor = cnt + NN;                     // [NN]    -> single memset)
    int*   off    = cursor + NN;                  // [NN+1]
    int*   bsum   = off + NN + 1;                 // [256]
    int*   srow   = bsum + 256;                   // [NE]
    float* snorm  = (float*)(srow + NE);          // [NE]

    const int* rows = ei;
    const int* cols = ei + NE;

    dim3 blk(256);
    const int NB = (NN + 255) / 256;   // 196

    // --- single prep kernel: xb, prev1->AP1, all weight transforms ---
    const long PREP = MP * 256 + (long)NN * 256 + 65536 + 3 * 32768 + 524288 + 131072;
    prep_all<<<(int)((PREP + 255) / 256), blk, 0, stream>>>(
        x, prev1, pre1_W, pre2_W, conv1_W, conv2_W,
        g1_Wih, g1_Whh, g2_Wih, g2_Whh,
        R1, AP1, pre1T, pre2T, conv1T, conv2T, W1g1, W1g2);

    // --- CSR build (once, reused by both layers) ---
    hipMemsetAsync(cnt, 0, 2 * NN * sizeof(int), stream);   // cnt + cursor
    cnt_kernel<<<(NE + 255) / 256, blk, 0, stream>>>(cols, cnt, NE);
    scan1<<<NB, blk, 0, stream>>>(cnt, off, bsum, dinv, NN);
    scan2<<<1, blk, 0, stream>>>(bsum, NB);
    scan3<<<NB, blk, 0, stream>>>(off, bsum, NN);
    fill_csr<<<(NE + 255) / 256, blk, 0, stream>>>(rows, cols, dinv, off, cursor, srow, snorm, NE);

    // --- dense pre-layers ---
    gemm_mfma<1, 256><<<782, blk, 0, stream>>>(R1, pre1T, pre1_b, R2, 256, 2, 782);
    gemm_mfma<1, 256><<<391, blk, 0, stream>>>(R2, pre2T, pre2_b, R3, 128, 1, 391);

    // --- GCN1: aggregate on 128-dim h2 (raw), then conv1 GEMM -> AP1 left ---
    gather_agg<128, false, false><<<(NN + 3) / 4, blk, 0, stream>>>(
        R3, off, srow, snorm, dinv, nullptr, nullptr, R1, NN);
    gemm_mfma<1, 128><<<782, blk, 0, stream>>>(R1, conv1T, conv1_b, AP1, 512, 2, 782);

    // --- GRU1 (wide fused, K-split, pipelined) -> emb1 fp32 + emb1b (R2) ---
    gru_wide<256, true><<<3128, blk, 0, stream>>>(AP1, W1g1, prev1, g1_bih, g1_bhh,
                                                  emb1, R2, NN, 8, 3128);

    // --- conv2 ---
    gemm_mfma<0, 256><<<391, blk, 0, stream>>>(R2, conv2T, nullptr, R3, 128, 1, 391);

    // --- GCN2: aggregate (fused bias+lrelu) + prev2 copy -> AP2 ---
    gather_agg<256, true, true><<<(NN + 3) / 4, blk, 0, stream>>>(
        R3, off, srow, snorm, dinv, conv2_b, prev2, AP2, NN);

    // --- GRU2 (wide fused, K-split, pipelined) -> emb2 fp32 + emb2b (R3) ---
    gru_wide<128, true><<<1564, blk, 0, stream>>>(AP2, W1g2, prev2, g2_bih, g2_bhh,
                                                  emb2, R3, NN, 4, 1564);

    // --- edge scores (bf16 gather) ---
    edge_score_b<<<NQ / 4, blk, 0, stream>>>(R3, eli, eattr, post_W, post_b, scores, NQ);
}